// Round 1
// baseline (3383.719 us; speedup 1.0000x reference)
//
#include <hip/hip_runtime.h>

// ---------------------------------------------------------------------------
// MyModel: BiLSTM1(token) + maxpool -> softmax7/avg_lab -> MLP -> top-k gate
//          -> BiLSTM2(sentence seq, batch=1) -> log_softmax CE + penalty
// N=1024, L=128, D=300, H=150, G=4H=600
// ---------------------------------------------------------------------------

typedef _Float16 f16;
typedef _Float16 half8 __attribute__((ext_vector_type(8)));
typedef float    floatx4 __attribute__((ext_vector_type(4)));

#define MFMA16(a, b, c) __builtin_amdgcn_mfma_f32_16x16x32_f16((a), (b), (c), 0, 0, 0)

__device__ __forceinline__ float sigm_(float x) { return 1.0f / (1.0f + __expf(-x)); }
// tanh(x) = 1 - 2/(1+e^{2x}) : stable at both ends (inf -> 1, 0 -> -1)
__device__ __forceinline__ float tanh_(float x) { return 1.0f - 2.0f / (1.0f + __expf(2.0f * x)); }

// ---------------------------------------------------------------------------
// K0a: pack fp32 weights into zero-padded f16 buffers.
// jobs 0..4: input-side GEMM B matrices ([out,in] native = NT layout)
// jobs 5..8: recurrent w_hh -> [640][160] f16 (pad gates 600->640, k 150->160)
// ---------------------------------------------------------------------------
struct PackA { const float* s[9]; f16* d[9]; };

__global__ void pack_k(PackA pa) {
    const int rows[9] = {600, 600, 300, 600, 600, 600, 600, 600, 600};
    const int cols[9] = {300, 300, 600, 300, 300, 150, 150, 150, 150};
    const int R[9]    = {640, 640, 320, 640, 640, 640, 640, 640, 640};
    const int C[9]    = {320, 320, 640, 320, 320, 160, 160, 160, 160};
    int j = blockIdx.y;
    int idx = blockIdx.x * 256 + threadIdx.x;
    int RC = R[j] * C[j];
    if (idx >= RC) return;
    int r = idx / C[j], c = idx % C[j];
    float v = (r < rows[j] && c < cols[j]) ? pa.s[j][r * cols[j] + c] : 0.0f;
    pa.d[j][idx] = (f16)v;
}

// K0b: exclusive prefix sum of lengths -> compact row offsets
__global__ __launch_bounds__(1024) void scan_k(const int* __restrict__ len, int* __restrict__ coff) {
    __shared__ int a[1024];
    int t = threadIdx.x;
    a[t] = len[t];
    __syncthreads();
    for (int off = 1; off < 1024; off <<= 1) {
        int v = (t >= off) ? a[t - off] : 0;
        __syncthreads();
        a[t] += v;
        __syncthreads();
    }
    coff[t] = a[t] - len[t];
}

// ---------------------------------------------------------------------------
// Generic NT GEMM: C[m][n] = sum_k A_f32[m][k] * B_f16[n][k]  (+bias, relu)
// M-tile 128 (4 waves x 32 rows), N per block = 320 (20 MFMA col-tiles),
// K-step 32, mfma_f32_16x16x32_f16.
// COMPACT: M-tile == one sentence (L=128); store only rows t < len[n] at
// compacted row coff[n]+t (f16).
// ---------------------------------------------------------------------------
template <bool RELU, bool STF16, bool COMPACT>
__global__ __launch_bounds__(256, 2) void gemm_nt(
    const float* __restrict__ A, int lda, int Keff, int Ksteps,
    const f16* __restrict__ B, const float* __restrict__ bias, int nbias,
    float* __restrict__ Cf, f16* __restrict__ Ch, int ldc,
    const int* __restrict__ len, const int* __restrict__ coff) {
    __shared__ f16 As[128][40];   // +8 pad: stride 80B = 20 banks, conflict-free frag reads
    __shared__ f16 Bs[320][40];

    const int tid = threadIdx.x;
    const int m0 = blockIdx.x * 128;
    const int n0 = blockIdx.y * 320;
    const int ldb = Ksteps * 32;
    const int wv = tid >> 6, ln = tid & 63;
    const int lq = ln >> 4, lr = ln & 15;

    int sn = 0, ln_ = 0x7fffffff, co = 0;
    if (COMPACT) { sn = m0 >> 7; ln_ = len[sn]; co = coff[sn]; }
    const bool act = !COMPACT || (wv * 32 < ln_);  // wave-level skip for dead rows

    floatx4 acc[2][20];
#pragma unroll
    for (int s = 0; s < 2; ++s)
#pragma unroll
        for (int nt = 0; nt < 20; ++nt) acc[s][nt] = 0;

    for (int kt = 0; kt < Ksteps; ++kt) {
        // ---- A tile: 128 rows x 32 k, fp32 -> f16
        {
            int r = tid >> 1, c0 = (tid & 1) * 16;
            int gk = kt * 32 + c0;
            const float* ap = A + (size_t)(m0 + r) * lda + gk;
            float v[16];
            if (gk + 16 <= Keff) {
                const float4* p4 = (const float4*)ap;
                float4 a0 = p4[0], a1 = p4[1], a2 = p4[2], a3 = p4[3];
                v[0]=a0.x; v[1]=a0.y; v[2]=a0.z; v[3]=a0.w;
                v[4]=a1.x; v[5]=a1.y; v[6]=a1.z; v[7]=a1.w;
                v[8]=a2.x; v[9]=a2.y; v[10]=a2.z; v[11]=a2.w;
                v[12]=a3.x; v[13]=a3.y; v[14]=a3.z; v[15]=a3.w;
            } else {
#pragma unroll
                for (int j = 0; j < 16; ++j) v[j] = (gk + j < Keff) ? ap[j] : 0.0f;
            }
            half8 h0, h1;
#pragma unroll
            for (int j = 0; j < 8; ++j) { h0[j] = (f16)v[j]; h1[j] = (f16)v[8 + j]; }
            *(half8*)&As[r][c0] = h0;
            *(half8*)&As[r][c0 + 8] = h1;
        }
        // ---- B tile: 320 rows x 32 k (pre-padded f16)
        {
            int q = tid & 3;
#pragma unroll
            for (int i = 0; i < 5; ++i) {
                int rb = (tid >> 2) + i * 64;
                half8 bv = *(const half8*)(B + (size_t)(n0 + rb) * ldb + kt * 32 + q * 8);
                *(half8*)&Bs[rb][q * 8] = bv;
            }
        }
        __syncthreads();
        if (act) {
            half8 af0 = *(const half8*)&As[wv * 32 + lr][lq * 8];
            half8 af1 = *(const half8*)&As[wv * 32 + 16 + lr][lq * 8];
#pragma unroll
            for (int nt = 0; nt < 20; ++nt) {
                half8 bf = *(const half8*)&Bs[nt * 16 + lr][lq * 8];
                acc[0][nt] = MFMA16(af0, bf, acc[0][nt]);
                acc[1][nt] = MFMA16(af1, bf, acc[1][nt]);
            }
        }
        __syncthreads();
    }
    if (!act) return;
    // ---- epilogue: C layout col=lane&15, row=quad*4+reg (verified m89)
#pragma unroll
    for (int s = 0; s < 2; ++s)
#pragma unroll
        for (int nt = 0; nt < 20; ++nt)
#pragma unroll
            for (int rr = 0; rr < 4; ++rr) {
                int t = wv * 32 + s * 16 + lq * 4 + rr;  // row within tile
                int gm = m0 + t;
                int col = n0 + nt * 16 + lr;
                float v = acc[s][nt][rr];
                if (bias && col < nbias) v += bias[col];
                if (RELU) v = fmaxf(v, 0.0f);
                if (STF16) {
                    if (COMPACT) {
                        if (t < ln_) Ch[(size_t)(co + t) * ldc + col] = (f16)v;
                    } else {
                        Ch[(size_t)gm * ldc + col] = (f16)v;
                    }
                } else {
                    Cf[(size_t)gm * ldc + col] = v;
                }
            }
}

// ---------------------------------------------------------------------------
// K2: LSTM1 recurrence, 16 sentences per WG, w_hh as register B-fragments.
// Gates(16x600) = Xg(precomputed, bias baked) + h @ w_hh.T via MFMA.
// Max-pool over t < len folded in. dir=0 fwd, dir=1 bwd (reads Xg reversed).
// ---------------------------------------------------------------------------
__global__ __launch_bounds__(512, 2) void lstm1_k(
    const f16* __restrict__ Xg,   // [total_compact][640]
    const f16* __restrict__ Whh,  // [640][160]
    float* __restrict__ sent,     // [1024][300]
    const int* __restrict__ len, const int* __restrict__ coff, int dir) {
    __shared__ float gates[16][644];  // pad 644: quad rows land on distinct banks
    __shared__ f16 hbuf[16][168];     // pad k 150->160(zero), stride 168 for banks
    __shared__ float cbuf[16][152];
    __shared__ float pool[16][152];
    __shared__ int lens_s[16], coff_s[16];

    const int tid = threadIdx.x;
    const int wv = tid >> 6, ln = tid & 63;
    const int lq = ln >> 4, lr = ln & 15;
    const int sb = blockIdx.x * 16;

    if (tid < 16) { lens_s[tid] = len[sb + tid]; coff_s[tid] = coff[sb + tid]; }
    for (int i = tid; i < 16 * 168; i += 512) (&hbuf[0][0])[i] = (f16)0.0f;
    for (int i = tid; i < 16 * 152; i += 512) { (&cbuf[0][0])[i] = 0.0f; (&pool[0][0])[i] = -1e30f; }
    __syncthreads();

    int maxlen = 0;
#pragma unroll
    for (int j = 0; j < 16; ++j) maxlen = max(maxlen, lens_s[j]);

    const int nb = wv * 80;  // 8 waves x 5 col-tiles = 640 cols
    half8 bf[5][5];          // [nt][kt] : B[k][n] = w_hh[n][k]
#pragma unroll
    for (int nt = 0; nt < 5; ++nt)
#pragma unroll
        for (int kt = 0; kt < 5; ++kt)
            bf[nt][kt] = *(const half8*)(Whh + (size_t)(nb + nt * 16 + lr) * 160 + kt * 32 + lq * 8);

    for (int t = 0; t < maxlen; ++t) {
        half8 af[5];
#pragma unroll
        for (int kt = 0; kt < 5; ++kt) af[kt] = *(const half8*)&hbuf[lr][kt * 32 + lq * 8];
#pragma unroll
        for (int nt = 0; nt < 5; ++nt) {
            int col = nb + nt * 16 + lr;
            floatx4 acc;
#pragma unroll
            for (int rr = 0; rr < 4; ++rr) {
                int m = lq * 4 + rr;
                int te = dir ? max(lens_s[m] - 1 - t, 0) : min(t, lens_s[m] - 1);
                acc[rr] = (float)Xg[(size_t)(coff_s[m] + te) * 640 + col];
            }
#pragma unroll
            for (int kt = 0; kt < 5; ++kt) acc = MFMA16(af[kt], bf[nt][kt], acc);
#pragma unroll
            for (int rr = 0; rr < 4; ++rr) gates[lq * 4 + rr][col] = acc[rr];
        }
        __syncthreads();
        for (int idx = tid; idx < 2400; idx += 512) {
            int j = idx >> 4, m = idx & 15;
            float gi = gates[m][j], gf = gates[m][150 + j];
            float gg = gates[m][300 + j], go = gates[m][450 + j];
            float cn = sigm_(gf) * cbuf[m][j] + sigm_(gi) * tanh_(gg);
            float hn = sigm_(go) * tanh_(cn);
            cbuf[m][j] = cn;
            hbuf[m][j] = (f16)hn;
            if (t < lens_s[m]) pool[m][j] = fmaxf(pool[m][j], hn);
        }
        __syncthreads();
    }
    for (int idx = tid; idx < 2400; idx += 512) {
        int j = idx >> 4, m = idx & 15;
        sent[(size_t)(sb + m) * 300 + (dir ? 150 : 0) + j] = pool[m][j];
    }
}

// ---------------------------------------------------------------------------
// K4a: per sentence: ex softmax(7), ex_pre argmax, avg_lab, build A2 fp32
// A2 = [sent(300) | avg_lab(300) | zeros(40)]  (one wave per row)
// ---------------------------------------------------------------------------
__global__ void k4a(const float* __restrict__ sent, const float* __restrict__ w_ex,
                    const float* __restrict__ b_ex, const float* __restrict__ lab,
                    float* __restrict__ A2, int* __restrict__ expre) {
    int n = blockIdx.x, l = threadIdx.x;
    float s[5];
#pragma unroll
    for (int i = 0; i < 5; ++i) { int d = l + 64 * i; s[i] = (d < 300) ? sent[(size_t)n * 300 + d] : 0.0f; }
    float logit[7];
#pragma unroll
    for (int c = 0; c < 7; ++c) {
        float p = 0.0f;
#pragma unroll
        for (int i = 0; i < 5; ++i) { int d = l + 64 * i; if (d < 300) p += s[i] * w_ex[c * 300 + d]; }
#pragma unroll
        for (int off = 32; off > 0; off >>= 1) p += __shfl_xor(p, off);
        logit[c] = p + b_ex[c];
    }
    float mx = logit[0];
#pragma unroll
    for (int c = 1; c < 7; ++c) mx = fmaxf(mx, logit[c]);
    float e[7], ssum = 0.0f;
#pragma unroll
    for (int c = 0; c < 7; ++c) { e[c] = expf(logit[c] - mx); ssum += e[c]; }
    int best = 0;
#pragma unroll
    for (int c = 1; c < 7; ++c) if (logit[c] > logit[best]) best = c;
    if (l == 0) expre[n] = best;
    float inv = 1.0f / ssum;
#pragma unroll
    for (int i = 0; i < 5; ++i) {
        int d = l + 64 * i;
        if (d < 300) {
            float al = 0.0f;
#pragma unroll
            for (int c = 0; c < 7; ++c) al += e[c] * inv * lab[c * 300 + d];
            A2[(size_t)n * 640 + d] = s[i];
            A2[(size_t)n * 640 + 300 + d] = al;
        }
    }
    if (l < 40) A2[(size_t)n * 640 + 600 + l] = 0.0f;
}

// ---------------------------------------------------------------------------
// K5: score softmax over N, exact top-512 (rank with jax tie-order), penalty
// partial, mixed = in_top ? joint : sent (fp32, zero-padded to 320)
// ---------------------------------------------------------------------------
__global__ __launch_bounds__(1024) void k5(const float* __restrict__ joint,
                                           const float* __restrict__ sent,
                                           const float* __restrict__ w_sc,
                                           const float* __restrict__ b_sc,
                                           const int* __restrict__ gold,
                                           const int* __restrict__ expre,
                                           float* __restrict__ mixed,
                                           float* __restrict__ pen_out) {
    __shared__ float arr[1024];
    __shared__ float red[1024];
    int n = threadIdx.x;
    float sc = b_sc[0];
    for (int d = 0; d < 300; ++d) sc += joint[(size_t)n * 320 + d] * w_sc[d];
    float sg = 1.0f / (1.0f + expf(-sc));
    arr[n] = sg;
    red[n] = sg;
    __syncthreads();
    for (int s = 512; s > 0; s >>= 1) { if (n < s) red[n] = fmaxf(red[n], red[n + s]); __syncthreads(); }
    float mx = red[0];
    __syncthreads();
    float ex = expf(sg - mx);
    red[n] = ex;
    __syncthreads();
    for (int s = 512; s > 0; s >>= 1) { if (n < s) red[n] += red[n + s]; __syncthreads(); }
    float score = ex / red[0];
    __syncthreads();
    // rank (value desc, index asc) == jax.lax.top_k selection
    int cnt = 0;
    for (int j = 0; j < 1024; ++j) {
        float vj = arr[j];
        cnt += (vj > sg) || (vj == sg && j < n);
    }
    bool top = cnt < 512;
    bool wrong = gold[n] != expre[n];
    float contrib = wrong ? (top ? 1.5f * score : 0.0f) : (top ? 0.0f : -1.5f * score);
    red[n] = contrib;
    __syncthreads();
    for (int s = 512; s > 0; s >>= 1) { if (n < s) red[n] += red[n + s]; __syncthreads(); }
    if (n == 0) pen_out[0] = red[0];
    for (int d = 0; d < 300; ++d)
        mixed[(size_t)n * 320 + d] = top ? joint[(size_t)n * 320 + d] : sent[(size_t)n * 300 + d];
    for (int d = 300; d < 320; ++d) mixed[(size_t)n * 320 + d] = 0.0f;
}

// ---------------------------------------------------------------------------
// K7: LSTM2, batch=1, 1024 sequential steps. 2 WGs (fwd/bwd). w_hh in
// register B-fragments; every lane loads the same h as A -> all 16 C rows
// identical -> quad 0 publishes gates.
// ---------------------------------------------------------------------------
__global__ __launch_bounds__(512, 2) void lstm2_k(
    const f16* __restrict__ G2f, const f16* __restrict__ G2b,
    const f16* __restrict__ H2f, const f16* __restrict__ H2b,
    float* __restrict__ out2) {
    const int dir = blockIdx.x;
    const f16* G2 = dir ? G2b : G2f;
    const f16* Whh = dir ? H2b : H2f;
    __shared__ float gl[640];
    __shared__ f16 hl[168];
    __shared__ float cl[150];

    const int tid = threadIdx.x;
    const int wv = tid >> 6, ln = tid & 63;
    const int lq = ln >> 4, lr = ln & 15;
    for (int i = tid; i < 168; i += 512) hl[i] = (f16)0.0f;
    if (tid < 150) cl[tid] = 0.0f;
    __syncthreads();

    const int nb = wv * 80;
    half8 bf[5][5];
#pragma unroll
    for (int nt = 0; nt < 5; ++nt)
#pragma unroll
        for (int kt = 0; kt < 5; ++kt)
            bf[nt][kt] = *(const half8*)(Whh + (size_t)(nb + nt * 16 + lr) * 160 + kt * 32 + lq * 8);

    for (int step = 0; step < 1024; ++step) {
        int row = dir ? (1023 - step) : step;
        half8 af[5];
#pragma unroll
        for (int kt = 0; kt < 5; ++kt) af[kt] = *(const half8*)&hl[kt * 32 + lq * 8];
#pragma unroll
        for (int nt = 0; nt < 5; ++nt) {
            int col = nb + nt * 16 + lr;
            float g0 = (float)G2[(size_t)row * 640 + col];
            floatx4 acc = {g0, g0, g0, g0};
#pragma unroll
            for (int kt = 0; kt < 5; ++kt) acc = MFMA16(af[kt], bf[nt][kt], acc);
            if (lq == 0) gl[col] = acc[0];
        }
        __syncthreads();
        if (tid < 150) {
            int j = tid;
            float gi = gl[j], gf = gl[150 + j], gg = gl[300 + j], go = gl[450 + j];
            float cn = sigm_(gf) * cl[j] + sigm_(gi) * tanh_(gg);
            float hn = sigm_(go) * tanh_(cn);
            cl[j] = cn;
            hl[j] = (f16)hn;
            out2[(size_t)row * 300 + dir * 150 + j] = hn;
        }
        __syncthreads();
    }
}

// ---------------------------------------------------------------------------
// K8: tag logits, log_softmax, argmax -> d_out[0..1023]; CE sum + pen -> [1024]
// ---------------------------------------------------------------------------
__global__ __launch_bounds__(1024) void k8(const float* __restrict__ out2,
                                           const float* __restrict__ w_tag,
                                           const float* __restrict__ b_tag,
                                           const int* __restrict__ gold,
                                           const float* __restrict__ pen,
                                           float* __restrict__ dout) {
    __shared__ float red[1024];
    int n = threadIdx.x;
    float lg[7];
#pragma unroll
    for (int c = 0; c < 7; ++c) lg[c] = b_tag[c];
    for (int d = 0; d < 300; ++d) {
        float od = out2[(size_t)n * 300 + d];
#pragma unroll
        for (int c = 0; c < 7; ++c) lg[c] += od * w_tag[c * 300 + d];
    }
    float mx = lg[0];
#pragma unroll
    for (int c = 1; c < 7; ++c) mx = fmaxf(mx, lg[c]);
    float se = 0.0f;
#pragma unroll
    for (int c = 0; c < 7; ++c) se += expf(lg[c] - mx);
    float lse = logf(se);
    int best = 0;
#pragma unroll
    for (int c = 1; c < 7; ++c) if (lg[c] > lg[best]) best = c;
    dout[n] = (float)best;
    red[n] = -(lg[gold[n]] - mx - lse);
    __syncthreads();
    for (int s = 512; s > 0; s >>= 1) { if (n < s) red[n] += red[n + s]; __syncthreads(); }
    if (n == 0) dout[1024] = red[0] + pen[0];
}

// ---------------------------------------------------------------------------
extern "C" void kernel_launch(void* const* d_in, const int* in_sizes, int n_in,
                              void* d_out, int out_size, void* d_ws, size_t ws_size,
                              hipStream_t stream) {
    const float* x       = (const float*)d_in[0];
    const int*   lengths = (const int*)d_in[1];
    const int*   gold    = (const int*)d_in[2];
    const float* w1f_ih  = (const float*)d_in[3];
    const float* w1f_hh  = (const float*)d_in[4];
    const float* b1f     = (const float*)d_in[5];
    const float* w1b_ih  = (const float*)d_in[6];
    const float* w1b_hh  = (const float*)d_in[7];
    const float* b1b     = (const float*)d_in[8];
    const float* lab     = (const float*)d_in[9];
    const float* w_ex    = (const float*)d_in[10];
    const float* b_ex    = (const float*)d_in[11];
    const float* w_mlp   = (const float*)d_in[12];
    const float* b_mlp   = (const float*)d_in[13];
    const float* w_sc    = (const float*)d_in[14];
    const float* b_sc    = (const float*)d_in[15];
    const float* w2f_ih  = (const float*)d_in[16];
    const float* w2f_hh  = (const float*)d_in[17];
    const float* b2f     = (const float*)d_in[18];
    const float* w2b_ih  = (const float*)d_in[19];
    const float* w2b_hh  = (const float*)d_in[20];
    const float* b2b     = (const float*)d_in[21];
    const float* w_tag   = (const float*)d_in[22];
    const float* b_tag   = (const float*)d_in[23];
    float* dout = (float*)d_out;
    char* ws = (char*)d_ws;

    // ---- workspace layout (256B aligned), ~181 MB peak
    size_t o = 0;
    auto alloc = [&](size_t bytes) { size_t r = o; o += (bytes + 255) & ~(size_t)255; return r; };
    size_t XG   = alloc((size_t)131072 * 640 * 2);  // compacted gate precompute (reused fwd/bwd)
    size_t W1F  = alloc(640 * 320 * 2);
    size_t W1B  = alloc(640 * 320 * 2);
    size_t WMLP = alloc(320 * 640 * 2);
    size_t W2F  = alloc(640 * 320 * 2);
    size_t W2B  = alloc(640 * 320 * 2);
    size_t H1F  = alloc(640 * 160 * 2);
    size_t H1B  = alloc(640 * 160 * 2);
    size_t H2F  = alloc(640 * 160 * 2);
    size_t H2B  = alloc(640 * 160 * 2);
    size_t COFF = alloc(1024 * 4);
    size_t SENT = alloc((size_t)1024 * 300 * 4);
    size_t A2   = alloc((size_t)1024 * 640 * 4);
    size_t EXP  = alloc(1024 * 4);
    size_t JNT  = alloc((size_t)1024 * 320 * 4);
    size_t MIX  = alloc((size_t)1024 * 320 * 4);
    size_t G2F  = alloc((size_t)1024 * 640 * 2);
    size_t G2B  = alloc((size_t)1024 * 640 * 2);
    size_t OUT2 = alloc((size_t)1024 * 300 * 4);
    size_t PEN  = alloc(256);
    (void)ws_size; (void)in_sizes; (void)n_in; (void)out_size;

    // ---- K0: pack weights to f16, scan lengths
    PackA pa;
    pa.s[0] = w1f_ih; pa.d[0] = (f16*)(ws + W1F);
    pa.s[1] = w1b_ih; pa.d[1] = (f16*)(ws + W1B);
    pa.s[2] = w_mlp;  pa.d[2] = (f16*)(ws + WMLP);
    pa.s[3] = w2f_ih; pa.d[3] = (f16*)(ws + W2F);
    pa.s[4] = w2b_ih; pa.d[4] = (f16*)(ws + W2B);
    pa.s[5] = w1f_hh; pa.d[5] = (f16*)(ws + H1F);
    pa.s[6] = w1b_hh; pa.d[6] = (f16*)(ws + H1B);
    pa.s[7] = w2f_hh; pa.d[7] = (f16*)(ws + H2F);
    pa.s[8] = w2b_hh; pa.d[8] = (f16*)(ws + H2B);
    pack_k<<<dim3(800, 9), 256, 0, stream>>>(pa);
    scan_k<<<1, 1024, 0, stream>>>(lengths, (int*)(ws + COFF));

    // ---- LSTM1 forward: Xg = x @ w1f_ih.T + b1f (compacted), then recurrence
    gemm_nt<false, true, true><<<dim3(1024, 2), 256, 0, stream>>>(
        x, 300, 300, 10, (const f16*)(ws + W1F), b1f, 600,
        nullptr, (f16*)(ws + XG), 640, lengths, (const int*)(ws + COFF));
    lstm1_k<<<64, 512, 0, stream>>>((const f16*)(ws + XG), (const f16*)(ws + H1F),
                                    (float*)(ws + SENT), lengths, (const int*)(ws + COFF), 0);
    // ---- LSTM1 backward (same Xg buffer; reads reversed rows per sentence)
    gemm_nt<false, true, true><<<dim3(1024, 2), 256, 0, stream>>>(
        x, 300, 300, 10, (const f16*)(ws + W1B), b1b, 600,
        nullptr, (f16*)(ws + XG), 640, lengths, (const int*)(ws + COFF));
    lstm1_k<<<64, 512, 0, stream>>>((const f16*)(ws + XG), (const f16*)(ws + H1B),
                                    (float*)(ws + SENT), lengths, (const int*)(ws + COFF), 1);

    // ---- middle stage
    k4a<<<1024, 64, 0, stream>>>((const float*)(ws + SENT), w_ex, b_ex, lab,
                                 (float*)(ws + A2), (int*)(ws + EXP));
    gemm_nt<true, false, false><<<dim3(8, 1), 256, 0, stream>>>(
        (const float*)(ws + A2), 640, 640, 20, (const f16*)(ws + WMLP), b_mlp, 300,
        (float*)(ws + JNT), nullptr, 320, nullptr, nullptr);
    k5<<<1, 1024, 0, stream>>>((const float*)(ws + JNT), (const float*)(ws + SENT),
                               w_sc, b_sc, gold, (const int*)(ws + EXP),
                               (float*)(ws + MIX), (float*)(ws + PEN));

    // ---- LSTM2 input gates then sequential recurrence (2 WGs)
    gemm_nt<false, true, false><<<dim3(8, 2), 256, 0, stream>>>(
        (const float*)(ws + MIX), 320, 320, 10, (const f16*)(ws + W2F), b2f, 600,
        nullptr, (f16*)(ws + G2F), 640, nullptr, nullptr);
    gemm_nt<false, true, false><<<dim3(8, 2), 256, 0, stream>>>(
        (const float*)(ws + MIX), 320, 320, 10, (const f16*)(ws + W2B), b2b, 600,
        nullptr, (f16*)(ws + G2B), 640, nullptr, nullptr);
    lstm2_k<<<2, 512, 0, stream>>>((const f16*)(ws + G2F), (const f16*)(ws + G2B),
                                   (const f16*)(ws + H2F), (const f16*)(ws + H2B),
                                   (float*)(ws + OUT2));

    // ---- loss + predictions
    k8<<<1, 1024, 0, stream>>>((const float*)(ws + OUT2), w_tag, b_tag, gold,
                               (const float*)(ws + PEN), dout);
}

// Round 2
// 2946.967 us; speedup vs baseline: 1.1482x; 1.1482x over previous
//
#include <hip/hip_runtime.h>

// ---------------------------------------------------------------------------
// MyModel: BiLSTM1(token) + maxpool -> softmax7/avg_lab -> MLP -> top-k gate
//          -> BiLSTM2(sentence seq, batch=1) -> log_softmax CE + penalty
// N=1024, L=128, D=300, H=150, G=4H=600
// ---------------------------------------------------------------------------

typedef _Float16 f16;
typedef _Float16 half8 __attribute__((ext_vector_type(8)));
typedef float    floatx4 __attribute__((ext_vector_type(4)));

#define MFMA16(a, b, c) __builtin_amdgcn_mfma_f32_16x16x32_f16((a), (b), (c), 0, 0, 0)

__device__ __forceinline__ float sigm_(float x) { return 1.0f / (1.0f + __expf(-x)); }
__device__ __forceinline__ float tanh_(float x) { return 1.0f - 2.0f / (1.0f + __expf(2.0f * x)); }

// ---------------------------------------------------------------------------
// K0a: pack fp32 weights into zero-padded f16 buffers.
// ---------------------------------------------------------------------------
struct PackA { const float* s[9]; f16* d[9]; };

__global__ void pack_k(PackA pa) {
    const int rows[9] = {600, 600, 300, 600, 600, 600, 600, 600, 600};
    const int cols[9] = {300, 300, 600, 300, 300, 150, 150, 150, 150};
    const int R[9]    = {640, 640, 320, 640, 640, 640, 640, 640, 640};
    const int C[9]    = {320, 320, 640, 320, 320, 160, 160, 160, 160};
    int j = blockIdx.y;
    int idx = blockIdx.x * 256 + threadIdx.x;
    int RC = R[j] * C[j];
    if (idx >= RC) return;
    int r = idx / C[j], c = idx % C[j];
    float v = (r < rows[j] && c < cols[j]) ? pa.s[j][r * cols[j] + c] : 0.0f;
    pa.d[j][idx] = (f16)v;
}

// K0b: exclusive prefix sum of lengths -> compact row offsets
__global__ __launch_bounds__(1024) void scan_k(const int* __restrict__ len, int* __restrict__ coff) {
    __shared__ int a[1024];
    int t = threadIdx.x;
    a[t] = len[t];
    __syncthreads();
    for (int off = 1; off < 1024; off <<= 1) {
        int v = (t >= off) ? a[t - off] : 0;
        __syncthreads();
        a[t] += v;
        __syncthreads();
    }
    coff[t] = a[t] - len[t];
}

// ---------------------------------------------------------------------------
// Dual-B NT GEMM (f16 out): blockIdx.y selects {B0,bias0,C0} (y<2) or
// {B1,bias1,C1}; n0=(y&1)*320. M-tile 128 = one sentence when COMPACT.
// Dead-row A loads skipped (garbage rows only pollute discarded C rows).
// ---------------------------------------------------------------------------
template <bool COMPACT>
__global__ __launch_bounds__(256, 2) void gemm2_nt(
    const float* __restrict__ A, int lda, int Keff, int Ksteps,
    const f16* __restrict__ B0, const float* __restrict__ bias0, f16* __restrict__ C0,
    const f16* __restrict__ B1, const float* __restrict__ bias1, f16* __restrict__ C1,
    int ldc, const int* __restrict__ len, const int* __restrict__ coff) {
    __shared__ f16 As[128][40];
    __shared__ f16 Bs[320][40];

    const int tid = threadIdx.x;
    const int m0 = blockIdx.x * 128;
    const int sel = blockIdx.y >> 1;
    const int n0 = (blockIdx.y & 1) * 320;
    const f16* B = sel ? B1 : B0;
    const float* bias = sel ? bias1 : bias0;
    f16* Ch = sel ? C1 : C0;
    const int ldb = Ksteps * 32;
    const int wv = tid >> 6, ln = tid & 63;
    const int lq = ln >> 4, lr = ln & 15;

    int ln_ = 0x7fffffff, co = 0;
    if (COMPACT) { int sn = blockIdx.x; ln_ = len[sn]; co = coff[sn]; }
    const bool act = !COMPACT || (wv * 32 < ln_);

    floatx4 acc[2][20];
#pragma unroll
    for (int s = 0; s < 2; ++s)
#pragma unroll
        for (int nt = 0; nt < 20; ++nt) acc[s][nt] = 0;

    for (int kt = 0; kt < Ksteps; ++kt) {
        {
            int r = tid >> 1, c0 = (tid & 1) * 16;
            if (!COMPACT || r < ln_) {
                int gk = kt * 32 + c0;
                const float* ap = A + (size_t)(m0 + r) * lda + gk;
                float v[16];
                if (gk + 16 <= Keff) {
                    const float4* p4 = (const float4*)ap;
                    float4 a0 = p4[0], a1 = p4[1], a2 = p4[2], a3 = p4[3];
                    v[0]=a0.x; v[1]=a0.y; v[2]=a0.z; v[3]=a0.w;
                    v[4]=a1.x; v[5]=a1.y; v[6]=a1.z; v[7]=a1.w;
                    v[8]=a2.x; v[9]=a2.y; v[10]=a2.z; v[11]=a2.w;
                    v[12]=a3.x; v[13]=a3.y; v[14]=a3.z; v[15]=a3.w;
                } else {
#pragma unroll
                    for (int j = 0; j < 16; ++j) v[j] = (gk + j < Keff) ? ap[j] : 0.0f;
                }
                half8 h0, h1;
#pragma unroll
                for (int j = 0; j < 8; ++j) { h0[j] = (f16)v[j]; h1[j] = (f16)v[8 + j]; }
                *(half8*)&As[r][c0] = h0;
                *(half8*)&As[r][c0 + 8] = h1;
            }
        }
        {
            int q = tid & 3;
#pragma unroll
            for (int i = 0; i < 5; ++i) {
                int rb = (tid >> 2) + i * 64;
                half8 bv = *(const half8*)(B + (size_t)(n0 + rb) * ldb + kt * 32 + q * 8);
                *(half8*)&Bs[rb][q * 8] = bv;
            }
        }
        __syncthreads();
        if (act) {
            half8 af0 = *(const half8*)&As[wv * 32 + lr][lq * 8];
            half8 af1 = *(const half8*)&As[wv * 32 + 16 + lr][lq * 8];
#pragma unroll
            for (int nt = 0; nt < 20; ++nt) {
                half8 bf = *(const half8*)&Bs[nt * 16 + lr][lq * 8];
                acc[0][nt] = MFMA16(af0, bf, acc[0][nt]);
                acc[1][nt] = MFMA16(af1, bf, acc[1][nt]);
            }
        }
        __syncthreads();
    }
    if (!act) return;
#pragma unroll
    for (int s = 0; s < 2; ++s)
#pragma unroll
        for (int nt = 0; nt < 20; ++nt)
#pragma unroll
            for (int rr = 0; rr < 4; ++rr) {
                int t = wv * 32 + s * 16 + lq * 4 + rr;
                int col = n0 + nt * 16 + lr;
                float v = acc[s][nt][rr];
                if (col < 600) v += bias[col];
                if (COMPACT) {
                    if (t < ln_) Ch[(size_t)(co + t) * ldc + col] = (f16)v;
                } else {
                    Ch[(size_t)(m0 + t) * ldc + col] = (f16)v;
                }
            }
}

// ---------------------------------------------------------------------------
// Single-output NT GEMM fp32 out + bias + relu (MLP stage only)
// ---------------------------------------------------------------------------
__global__ __launch_bounds__(256, 2) void gemm_mlp(
    const float* __restrict__ A, int lda, int Ksteps,
    const f16* __restrict__ B, const float* __restrict__ bias,
    float* __restrict__ Cf, int ldc) {
    __shared__ f16 As[128][40];
    __shared__ f16 Bs[320][40];
    const int tid = threadIdx.x;
    const int m0 = blockIdx.x * 128;
    const int ldb = Ksteps * 32;
    const int wv = tid >> 6, ln = tid & 63;
    const int lq = ln >> 4, lr = ln & 15;

    floatx4 acc[2][20];
#pragma unroll
    for (int s = 0; s < 2; ++s)
#pragma unroll
        for (int nt = 0; nt < 20; ++nt) acc[s][nt] = 0;

    for (int kt = 0; kt < Ksteps; ++kt) {
        {
            int r = tid >> 1, c0 = (tid & 1) * 16;
            const float4* p4 = (const float4*)(A + (size_t)(m0 + r) * lda + kt * 32 + c0);
            float4 a0 = p4[0], a1 = p4[1], a2 = p4[2], a3 = p4[3];
            half8 h0, h1;
            h0[0]=(f16)a0.x; h0[1]=(f16)a0.y; h0[2]=(f16)a0.z; h0[3]=(f16)a0.w;
            h0[4]=(f16)a1.x; h0[5]=(f16)a1.y; h0[6]=(f16)a1.z; h0[7]=(f16)a1.w;
            h1[0]=(f16)a2.x; h1[1]=(f16)a2.y; h1[2]=(f16)a2.z; h1[3]=(f16)a2.w;
            h1[4]=(f16)a3.x; h1[5]=(f16)a3.y; h1[6]=(f16)a3.z; h1[7]=(f16)a3.w;
            *(half8*)&As[r][c0] = h0;
            *(half8*)&As[r][c0 + 8] = h1;
        }
        {
            int q = tid & 3;
#pragma unroll
            for (int i = 0; i < 5; ++i) {
                int rb = (tid >> 2) + i * 64;
                half8 bv = *(const half8*)(B + (size_t)rb * ldb + kt * 32 + q * 8);
                *(half8*)&Bs[rb][q * 8] = bv;
            }
        }
        __syncthreads();
        half8 af0 = *(const half8*)&As[wv * 32 + lr][lq * 8];
        half8 af1 = *(const half8*)&As[wv * 32 + 16 + lr][lq * 8];
#pragma unroll
        for (int nt = 0; nt < 20; ++nt) {
            half8 bf = *(const half8*)&Bs[nt * 16 + lr][lq * 8];
            acc[0][nt] = MFMA16(af0, bf, acc[0][nt]);
            acc[1][nt] = MFMA16(af1, bf, acc[1][nt]);
        }
        __syncthreads();
    }
#pragma unroll
    for (int s = 0; s < 2; ++s)
#pragma unroll
        for (int nt = 0; nt < 20; ++nt)
#pragma unroll
            for (int rr = 0; rr < 4; ++rr) {
                int t = wv * 32 + s * 16 + lq * 4 + rr;
                int col = nt * 16 + lr;
                float v = acc[s][nt][rr];
                if (col < 600) v += bias[col];
                v = fmaxf(v, 0.0f);
                Cf[(size_t)(m0 + t) * ldc + col] = v;
            }
}

// ---------------------------------------------------------------------------
// K2: LSTM1 recurrence, 16 sentences/WG. Xg prefetched into registers,
// dual-accumulator MFMA chains, w_hh register-resident B-fragments.
// dir = dirbase + blockIdx.y.
// ---------------------------------------------------------------------------
__global__ __launch_bounds__(512, 2) void lstm1_k(
    const f16* __restrict__ XgF, const f16* __restrict__ XgB,
    const f16* __restrict__ WhF, const f16* __restrict__ WhB,
    float* __restrict__ sent,
    const int* __restrict__ len, const int* __restrict__ coff, int dirbase) {
    const int dir = dirbase + blockIdx.y;
    const f16* Xg = dir ? XgB : XgF;
    const f16* Whh = dir ? WhB : WhF;
    __shared__ float gates[16][644];
    __shared__ f16 hbuf[16][168];
    __shared__ float cbuf[16][153];
    __shared__ float pool[16][153];
    __shared__ int lens_s[16], coff_s[16];

    const int tid = threadIdx.x;
    const int wv = tid >> 6, ln = tid & 63;
    const int lq = ln >> 4, lr = ln & 15;
    const int sb = blockIdx.x * 16;

    if (tid < 16) { lens_s[tid] = len[sb + tid]; coff_s[tid] = coff[sb + tid]; }
    for (int i = tid; i < 16 * 168; i += 512) (&hbuf[0][0])[i] = (f16)0.0f;
    for (int i = tid; i < 16 * 153; i += 512) { (&cbuf[0][0])[i] = 0.0f; (&pool[0][0])[i] = -1e30f; }
    __syncthreads();

    int maxlen = 0;
#pragma unroll
    for (int j = 0; j < 16; ++j) maxlen = max(maxlen, lens_s[j]);

    const int nb = wv * 80;
    half8 bf[5][5];
#pragma unroll
    for (int nt = 0; nt < 5; ++nt)
#pragma unroll
        for (int kt = 0; kt < 5; ++kt)
            bf[nt][kt] = *(const half8*)(Whh + (size_t)(nb + nt * 16 + lr) * 160 + kt * 32 + lq * 8);

    half8 af[5];
#pragma unroll
    for (int kt = 0; kt < 5; ++kt) af[kt] = *(const half8*)&hbuf[lr][kt * 32 + lq * 8];

    f16 xpre[5][4];
    // prefetch Xg row t=0
#pragma unroll
    for (int nt = 0; nt < 5; ++nt)
#pragma unroll
        for (int rr = 0; rr < 4; ++rr) {
            int m = lq * 4 + rr;
            int te = dir ? max(lens_s[m] - 1, 0) : 0;
            xpre[nt][rr] = Xg[(size_t)(coff_s[m] + te) * 640 + nb + nt * 16 + lr];
        }

    for (int t = 0; t < maxlen; ++t) {
#pragma unroll
        for (int nt = 0; nt < 5; ++nt) {
            int col = nb + nt * 16 + lr;
            floatx4 a0, a1;
#pragma unroll
            for (int rr = 0; rr < 4; ++rr) { a0[rr] = (float)xpre[nt][rr]; a1[rr] = 0.0f; }
            a0 = MFMA16(af[0], bf[nt][0], a0);
            a1 = MFMA16(af[1], bf[nt][1], a1);
            a0 = MFMA16(af[2], bf[nt][2], a0);
            a1 = MFMA16(af[3], bf[nt][3], a1);
            a0 = MFMA16(af[4], bf[nt][4], a0);
#pragma unroll
            for (int rr = 0; rr < 4; ++rr) gates[lq * 4 + rr][col] = a0[rr] + a1[rr];
        }
        // prefetch next step's Xg (te clamp makes t+1 == maxlen harmless)
#pragma unroll
        for (int nt = 0; nt < 5; ++nt)
#pragma unroll
            for (int rr = 0; rr < 4; ++rr) {
                int m = lq * 4 + rr;
                int te = dir ? max(lens_s[m] - 2 - t, 0) : min(t + 1, lens_s[m] - 1);
                xpre[nt][rr] = Xg[(size_t)(coff_s[m] + te) * 640 + nb + nt * 16 + lr];
            }
        __syncthreads();
        for (int idx = tid; idx < 2400; idx += 512) {
            int j = idx >> 4, m = idx & 15;
            float gi = gates[m][j], gf = gates[m][150 + j];
            float gg = gates[m][300 + j], go = gates[m][450 + j];
            float cn = sigm_(gf) * cbuf[m][j] + sigm_(gi) * tanh_(gg);
            float hn = sigm_(go) * tanh_(cn);
            cbuf[m][j] = cn;
            hbuf[m][j] = (f16)hn;
            if (t < lens_s[m]) pool[m][j] = fmaxf(pool[m][j], hn);
        }
        __syncthreads();
#pragma unroll
        for (int kt = 0; kt < 5; ++kt) af[kt] = *(const half8*)&hbuf[lr][kt * 32 + lq * 8];
    }
    for (int idx = tid; idx < 2400; idx += 512) {
        int j = idx >> 4, m = idx & 15;
        sent[(size_t)(sb + m) * 300 + (dir ? 150 : 0) + j] = pool[m][j];
    }
}

// ---------------------------------------------------------------------------
// K4a: per sentence: ex softmax(7), ex_pre argmax, avg_lab, build A2 fp32
// ---------------------------------------------------------------------------
__global__ void k4a(const float* __restrict__ sent, const float* __restrict__ w_ex,
                    const float* __restrict__ b_ex, const float* __restrict__ lab,
                    float* __restrict__ A2, int* __restrict__ expre) {
    int n = blockIdx.x, l = threadIdx.x;
    float s[5];
#pragma unroll
    for (int i = 0; i < 5; ++i) { int d = l + 64 * i; s[i] = (d < 300) ? sent[(size_t)n * 300 + d] : 0.0f; }
    float logit[7];
#pragma unroll
    for (int c = 0; c < 7; ++c) {
        float p = 0.0f;
#pragma unroll
        for (int i = 0; i < 5; ++i) { int d = l + 64 * i; if (d < 300) p += s[i] * w_ex[c * 300 + d]; }
#pragma unroll
        for (int off = 32; off > 0; off >>= 1) p += __shfl_xor(p, off);
        logit[c] = p + b_ex[c];
    }
    float mx = logit[0];
#pragma unroll
    for (int c = 1; c < 7; ++c) mx = fmaxf(mx, logit[c]);
    float e[7], ssum = 0.0f;
#pragma unroll
    for (int c = 0; c < 7; ++c) { e[c] = expf(logit[c] - mx); ssum += e[c]; }
    int best = 0;
#pragma unroll
    for (int c = 1; c < 7; ++c) if (logit[c] > logit[best]) best = c;
    if (l == 0) expre[n] = best;
    float inv = 1.0f / ssum;
#pragma unroll
    for (int i = 0; i < 5; ++i) {
        int d = l + 64 * i;
        if (d < 300) {
            float al = 0.0f;
#pragma unroll
            for (int c = 0; c < 7; ++c) al += e[c] * inv * lab[c * 300 + d];
            A2[(size_t)n * 640 + d] = s[i];
            A2[(size_t)n * 640 + 300 + d] = al;
        }
    }
    if (l < 40) A2[(size_t)n * 640 + 600 + l] = 0.0f;
}

// ---------------------------------------------------------------------------
// K5: score softmax over N, exact top-512, penalty partial, mixed
// ---------------------------------------------------------------------------
__global__ __launch_bounds__(1024) void k5(const float* __restrict__ joint,
                                           const float* __restrict__ sent,
                                           const float* __restrict__ w_sc,
                                           const float* __restrict__ b_sc,
                                           const int* __restrict__ gold,
                                           const int* __restrict__ expre,
                                           float* __restrict__ mixed,
                                           float* __restrict__ pen_out) {
    __shared__ float arr[1024];
    __shared__ float red[1024];
    int n = threadIdx.x;
    const float4* jr = (const float4*)(joint + (size_t)n * 320);
    const float4* wr = (const float4*)w_sc;
    float sc = b_sc[0];
    for (int q = 0; q < 75; ++q) {
        float4 a = jr[q], w = wr[q];
        sc += a.x * w.x + a.y * w.y + a.z * w.z + a.w * w.w;
    }
    float sg = 1.0f / (1.0f + expf(-sc));
    arr[n] = sg;
    red[n] = sg;
    __syncthreads();
    for (int s = 512; s > 0; s >>= 1) { if (n < s) red[n] = fmaxf(red[n], red[n + s]); __syncthreads(); }
    float mx = red[0];
    __syncthreads();
    float ex = expf(sg - mx);
    red[n] = ex;
    __syncthreads();
    for (int s = 512; s > 0; s >>= 1) { if (n < s) red[n] += red[n + s]; __syncthreads(); }
    float score = ex / red[0];
    __syncthreads();
    int cnt = 0;
    for (int j = 0; j < 1024; ++j) {
        float vj = arr[j];
        cnt += (vj > sg) || (vj == sg && j < n);
    }
    bool top = cnt < 512;
    bool wrong = gold[n] != expre[n];
    float contrib = wrong ? (top ? 1.5f * score : 0.0f) : (top ? 0.0f : -1.5f * score);
    red[n] = contrib;
    __syncthreads();
    for (int s = 512; s > 0; s >>= 1) { if (n < s) red[n] += red[n + s]; __syncthreads(); }
    if (n == 0) pen_out[0] = red[0];
    const float4* sr = (const float4*)(sent + (size_t)n * 300);
    float4* mr = (float4*)(mixed + (size_t)n * 320);
    for (int q = 0; q < 75; ++q) mr[q] = top ? jr[q] : sr[q];
    float4 z = {0, 0, 0, 0};
    for (int q = 75; q < 80; ++q) mr[q] = z;
}

// ---------------------------------------------------------------------------
// K7: LSTM2, batch=1, 1024 sequential steps, 2 WGs (fwd/bwd).
// One barrier/step: gate buffer double-buffered; elementwise computed
// redundantly by every wave (c state in per-wave registers) so each wave's
// own in-order LDS writes cover its subsequent h-fragment reads.
// G2 row prefetched into registers one step ahead.
// ---------------------------------------------------------------------------
__global__ __launch_bounds__(512, 2) void lstm2_k(
    const f16* __restrict__ G2f, const f16* __restrict__ G2b,
    const f16* __restrict__ H2f, const f16* __restrict__ H2b,
    float* __restrict__ out2) {
    const int dir = blockIdx.x;
    const f16* G2 = dir ? G2b : G2f;
    const f16* Whh = dir ? H2b : H2f;
    __shared__ float gl[2][656];
    __shared__ f16 hl[160];

    const int tid = threadIdx.x;
    const int wv = tid >> 6, ln = tid & 63;
    const int lq = ln >> 4, lr = ln & 15;
    for (int i = tid; i < 160; i += 512) hl[i] = (f16)0.0f;
    __syncthreads();

    // per-wave redundant c state: lane ln owns j = ln, ln+64, ln+128(<150)
    float c0 = 0.0f, c1 = 0.0f, c2 = 0.0f;

    const int nb = wv * 80;
    half8 bf[5][5];
#pragma unroll
    for (int nt = 0; nt < 5; ++nt)
#pragma unroll
        for (int kt = 0; kt < 5; ++kt)
            bf[nt][kt] = *(const half8*)(Whh + (size_t)(nb + nt * 16 + lr) * 160 + kt * 32 + lq * 8);

    half8 af[5];
#pragma unroll
    for (int kt = 0; kt < 5; ++kt) af[kt] = *(const half8*)&hl[kt * 32 + lq * 8];

    f16 gpre[5];
    {
        int row0 = dir ? 1023 : 0;
#pragma unroll
        for (int nt = 0; nt < 5; ++nt) gpre[nt] = G2[(size_t)row0 * 640 + nb + nt * 16 + lr];
    }

    for (int step = 0; step < 1024; ++step) {
        const int row = dir ? (1023 - step) : step;
        const int p = step & 1;
#pragma unroll
        for (int nt = 0; nt < 5; ++nt) {
            float g0 = (float)gpre[nt];
            floatx4 a0 = {g0, g0, g0, g0};
            floatx4 a1 = {0, 0, 0, 0};
            a0 = MFMA16(af[0], bf[nt][0], a0);
            a1 = MFMA16(af[1], bf[nt][1], a1);
            a0 = MFMA16(af[2], bf[nt][2], a0);
            a1 = MFMA16(af[3], bf[nt][3], a1);
            a0 = MFMA16(af[4], bf[nt][4], a0);
            if (lq == 0) gl[p][nb + nt * 16 + lr] = a0[0] + a1[0];
        }
        // prefetch next G2 row (latency hidden behind barrier + elementwise)
        {
            int nrow = dir ? max(1022 - step, 0) : min(step + 1, 1023);
#pragma unroll
            for (int nt = 0; nt < 5; ++nt) gpre[nt] = G2[(size_t)nrow * 640 + nb + nt * 16 + lr];
        }
        __syncthreads();
        // redundant elementwise in every wave
        {
            int j0 = ln, j1 = ln + 64, j2 = ln + 128;
            float gi0 = gl[p][j0], gf0 = gl[p][150 + j0], gg0 = gl[p][300 + j0], go0 = gl[p][450 + j0];
            float gi1 = gl[p][j1], gf1 = gl[p][150 + j1], gg1 = gl[p][300 + j1], go1 = gl[p][450 + j1];
            float cn0 = sigm_(gf0) * c0 + sigm_(gi0) * tanh_(gg0);
            float hn0 = sigm_(go0) * tanh_(cn0);
            c0 = cn0;
            float cn1 = sigm_(gf1) * c1 + sigm_(gi1) * tanh_(gg1);
            float hn1 = sigm_(go1) * tanh_(cn1);
            c1 = cn1;
            hl[j0] = (f16)hn0;
            hl[j1] = (f16)hn1;
            if (wv == 0) {
                out2[(size_t)row * 300 + dir * 150 + j0] = hn0;
                out2[(size_t)row * 300 + dir * 150 + j1] = hn1;
            }
            if (ln < 22) {
                float gi2 = gl[p][j2], gf2 = gl[p][150 + j2], gg2 = gl[p][300 + j2], go2 = gl[p][450 + j2];
                float cn2 = sigm_(gf2) * c2 + sigm_(gi2) * tanh_(gg2);
                float hn2 = sigm_(go2) * tanh_(cn2);
                c2 = cn2;
                hl[j2] = (f16)hn2;
                if (wv == 0) out2[(size_t)row * 300 + dir * 150 + j2] = hn2;
            }
        }
        // own-wave writes above are in-order with these reads (per-wave DS pipe)
#pragma unroll
        for (int kt = 0; kt < 5; ++kt) af[kt] = *(const half8*)&hl[kt * 32 + lq * 8];
    }
}

// ---------------------------------------------------------------------------
// K8: tag logits, log_softmax, argmax -> d_out[0..1023]; CE + pen -> [1024]
// ---------------------------------------------------------------------------
__global__ __launch_bounds__(1024) void k8(const float* __restrict__ out2,
                                           const float* __restrict__ w_tag,
                                           const float* __restrict__ b_tag,
                                           const int* __restrict__ gold,
                                           const float* __restrict__ pen,
                                           float* __restrict__ dout) {
    __shared__ float red[1024];
    int n = threadIdx.x;
    float lg[7];
#pragma unroll
    for (int c = 0; c < 7; ++c) lg[c] = b_tag[c];
    for (int d = 0; d < 300; ++d) {
        float od = out2[(size_t)n * 300 + d];
#pragma unroll
        for (int c = 0; c < 7; ++c) lg[c] += od * w_tag[c * 300 + d];
    }
    float mx = lg[0];
#pragma unroll
    for (int c = 1; c < 7; ++c) mx = fmaxf(mx, lg[c]);
    float se = 0.0f;
#pragma unroll
    for (int c = 0; c < 7; ++c) se += expf(lg[c] - mx);
    float lse = logf(se);
    int best = 0;
#pragma unroll
    for (int c = 1; c < 7; ++c) if (lg[c] > lg[best]) best = c;
    dout[n] = (float)best;
    red[n] = -(lg[gold[n]] - mx - lse);
    __syncthreads();
    for (int s = 512; s > 0; s >>= 1) { if (n < s) red[n] += red[n + s]; __syncthreads(); }
    if (n == 0) dout[1024] = red[0] + pen[0];
}

// ---------------------------------------------------------------------------
extern "C" void kernel_launch(void* const* d_in, const int* in_sizes, int n_in,
                              void* d_out, int out_size, void* d_ws, size_t ws_size,
                              hipStream_t stream) {
    const float* x       = (const float*)d_in[0];
    const int*   lengths = (const int*)d_in[1];
    const int*   gold    = (const int*)d_in[2];
    const float* w1f_ih  = (const float*)d_in[3];
    const float* w1f_hh  = (const float*)d_in[4];
    const float* b1f     = (const float*)d_in[5];
    const float* w1b_ih  = (const float*)d_in[6];
    const float* w1b_hh  = (const float*)d_in[7];
    const float* b1b     = (const float*)d_in[8];
    const float* lab     = (const float*)d_in[9];
    const float* w_ex    = (const float*)d_in[10];
    const float* b_ex    = (const float*)d_in[11];
    const float* w_mlp   = (const float*)d_in[12];
    const float* b_mlp   = (const float*)d_in[13];
    const float* w_sc    = (const float*)d_in[14];
    const float* b_sc    = (const float*)d_in[15];
    const float* w2f_ih  = (const float*)d_in[16];
    const float* w2f_hh  = (const float*)d_in[17];
    const float* b2f     = (const float*)d_in[18];
    const float* w2b_ih  = (const float*)d_in[19];
    const float* w2b_hh  = (const float*)d_in[20];
    const float* b2b     = (const float*)d_in[21];
    const float* w_tag   = (const float*)d_in[22];
    const float* b_tag   = (const float*)d_in[23];
    float* dout = (float*)d_out;
    char* ws = (char*)d_ws;

    size_t o = 0;
    auto alloc = [&](size_t bytes) { size_t r = o; o += (bytes + 255) & ~(size_t)255; return r; };
    size_t W1F  = alloc(640 * 320 * 2);
    size_t W1B  = alloc(640 * 320 * 2);
    size_t WMLP = alloc(320 * 640 * 2);
    size_t W2F  = alloc(640 * 320 * 2);
    size_t W2B  = alloc(640 * 320 * 2);
    size_t H1F  = alloc(640 * 160 * 2);
    size_t H1B  = alloc(640 * 160 * 2);
    size_t H2F  = alloc(640 * 160 * 2);
    size_t H2B  = alloc(640 * 160 * 2);
    size_t COFF = alloc(1024 * 4);
    size_t SENT = alloc((size_t)1024 * 300 * 4);
    size_t A2   = alloc((size_t)1024 * 640 * 4);
    size_t EXP  = alloc(1024 * 4);
    size_t JNT  = alloc((size_t)1024 * 320 * 4);
    size_t MIX  = alloc((size_t)1024 * 320 * 4);
    size_t G2F  = alloc((size_t)1024 * 640 * 2);
    size_t G2B  = alloc((size_t)1024 * 640 * 2);
    size_t OUT2 = alloc((size_t)1024 * 300 * 4);
    size_t PEN  = alloc(256);
    const size_t XGSZ = (size_t)131072 * 640 * 2;
    size_t XGF = alloc(XGSZ);
    bool bigws = (o + XGSZ) <= ws_size;        // ws_size fixed -> same path every call
    size_t XGB = bigws ? alloc(XGSZ) : XGF;
    (void)in_sizes; (void)n_in; (void)out_size;

    PackA pa;
    pa.s[0] = w1f_ih; pa.d[0] = (f16*)(ws + W1F);
    pa.s[1] = w1b_ih; pa.d[1] = (f16*)(ws + W1B);
    pa.s[2] = w_mlp;  pa.d[2] = (f16*)(ws + WMLP);
    pa.s[3] = w2f_ih; pa.d[3] = (f16*)(ws + W2F);
    pa.s[4] = w2b_ih; pa.d[4] = (f16*)(ws + W2B);
    pa.s[5] = w1f_hh; pa.d[5] = (f16*)(ws + H1F);
    pa.s[6] = w1b_hh; pa.d[6] = (f16*)(ws + H1B);
    pa.s[7] = w2f_hh; pa.d[7] = (f16*)(ws + H2F);
    pa.s[8] = w2b_hh; pa.d[8] = (f16*)(ws + H2B);
    pack_k<<<dim3(800, 9), 256, 0, stream>>>(pa);
    scan_k<<<1, 1024, 0, stream>>>(lengths, (int*)(ws + COFF));

    const int* coffp = (const int*)(ws + COFF);
    if (bigws) {
        // fused fwd+bwd input GEMM, then both lstm1 directions concurrently
        gemm2_nt<true><<<dim3(1024, 4), 256, 0, stream>>>(
            x, 300, 300, 10,
            (const f16*)(ws + W1F), b1f, (f16*)(ws + XGF),
            (const f16*)(ws + W1B), b1b, (f16*)(ws + XGB),
            640, lengths, coffp);
        lstm1_k<<<dim3(64, 2), 512, 0, stream>>>(
            (const f16*)(ws + XGF), (const f16*)(ws + XGB),
            (const f16*)(ws + H1F), (const f16*)(ws + H1B),
            (float*)(ws + SENT), lengths, coffp, 0);
    } else {
        gemm2_nt<true><<<dim3(1024, 2), 256, 0, stream>>>(
            x, 300, 300, 10,
            (const f16*)(ws + W1F), b1f, (f16*)(ws + XGF),
            (const f16*)(ws + W1F), b1f, (f16*)(ws + XGF),
            640, lengths, coffp);
        lstm1_k<<<dim3(64, 1), 512, 0, stream>>>(
            (const f16*)(ws + XGF), (const f16*)(ws + XGF),
            (const f16*)(ws + H1F), (const f16*)(ws + H1F),
            (float*)(ws + SENT), lengths, coffp, 0);
        gemm2_nt<true><<<dim3(1024, 2), 256, 0, stream>>>(
            x, 300, 300, 10,
            (const f16*)(ws + W1B), b1b, (f16*)(ws + XGF),
            (const f16*)(ws + W1B), b1b, (f16*)(ws + XGF),
            640, lengths, coffp);
        lstm1_k<<<dim3(64, 1), 512, 0, stream>>>(
            (const f16*)(ws + XGF), (const f16*)(ws + XGF),
            (const f16*)(ws + H1B), (const f16*)(ws + H1B),
            (float*)(ws + SENT), lengths, coffp, 1);
    }

    k4a<<<1024, 64, 0, stream>>>((const float*)(ws + SENT), w_ex, b_ex, lab,
                                 (float*)(ws + A2), (int*)(ws + EXP));
    gemm_mlp<<<8, 256, 0, stream>>>((const float*)(ws + A2), 640, 20,
                                    (const f16*)(ws + WMLP), b_mlp,
                                    (float*)(ws + JNT), 320);
    k5<<<1, 1024, 0, stream>>>((const float*)(ws + JNT), (const float*)(ws + SENT),
                               w_sc, b_sc, gold, (const int*)(ws + EXP),
                               (float*)(ws + MIX), (float*)(ws + PEN));

    // fused fwd+bwd LSTM2 input-gate GEMM
    gemm2_nt<false><<<dim3(8, 4), 256, 0, stream>>>(
        (const float*)(ws + MIX), 320, 320, 10,
        (const f16*)(ws + W2F), b2f, (f16*)(ws + G2F),
        (const f16*)(ws + W2B), b2b, (f16*)(ws + G2B),
        640, nullptr, nullptr);
    lstm2_k<<<2, 512, 0, stream>>>((const f16*)(ws + G2F), (const f16*)(ws + G2B),
                                   (const f16*)(ws + H2F), (const f16*)(ws + H2B),
                                   (float*)(ws + OUT2));

    k8<<<1, 1024, 0, stream>>>((const float*)(ws + OUT2), w_tag, b_tag, gold,
                               (const float*)(ws + PEN), dout);
}

// Round 3
// 1933.981 us; speedup vs baseline: 1.7496x; 1.5238x over previous
//
#include <hip/hip_runtime.h>

// ---------------------------------------------------------------------------
// MyModel: BiLSTM1(token) + maxpool -> softmax7/avg_lab -> MLP -> top-k gate
//          -> BiLSTM2(sentence seq, batch=1) -> log_softmax CE + penalty
// N=1024, L=128, D=300, H=150, G=4H=600
// ---------------------------------------------------------------------------

typedef _Float16 f16;
typedef _Float16 half8 __attribute__((ext_vector_type(8)));
typedef float    floatx4 __attribute__((ext_vector_type(4)));

#define MFMA16(a, b, c) __builtin_amdgcn_mfma_f32_16x16x32_f16((a), (b), (c), 0, 0, 0)
#define LOG2E 1.44269504f

__device__ __forceinline__ float rcp_(float x) { return __builtin_amdgcn_rcpf(x); }
__device__ __forceinline__ float ex2_(float x) { return __builtin_amdgcn_exp2f(x); }
// fast sigmoid/tanh: v_exp_f32 + v_rcp_f32 (~1ulp each; tolerance is ~41 abs)
__device__ __forceinline__ float sigm_(float x) { return rcp_(1.0f + ex2_(-LOG2E * x)); }
__device__ __forceinline__ float tanh_(float x) { return 1.0f - 2.0f * rcp_(1.0f + ex2_(2.0f * LOG2E * x)); }

// ---------------------------------------------------------------------------
// K0a: pack fp32 weights into zero-padded f16 buffers.
// mode 0: plain pad.  mode 1: LSTM2 input weights, gate-interleaved rows
// (row r=w*64+g*16+rr -> src gate g, j=w*16+rr) + bias folded at col 300.
// mode 2: LSTM2 recurrent weights, same row interleave.
// ---------------------------------------------------------------------------
struct PackA { const float* s[9]; f16* d[9]; const float* bb[2]; };

__global__ void pack_k(PackA pa) {
    const int R[9]    = {640, 640, 320, 640, 640, 640, 640, 640, 640};
    const int C[9]    = {320, 320, 640, 320, 320, 160, 160, 160, 160};
    const int rows[9] = {600, 600, 300, 600, 600, 600, 600, 600, 600};
    const int cols[9] = {300, 300, 600, 300, 300, 150, 150, 150, 150};
    const int mode[9] = {0, 0, 0, 1, 1, 0, 0, 2, 2};
    int j = blockIdx.y;
    int idx = blockIdx.x * 256 + threadIdx.x;
    int RC = R[j] * C[j];
    if (idx >= RC) return;
    int r = idx / C[j], c = idx % C[j];
    float v = 0.0f;
    if (mode[j] == 0) {
        if (r < rows[j] && c < cols[j]) v = pa.s[j][r * cols[j] + c];
    } else {
        int w = r >> 6, g = (r >> 4) & 3, rr = r & 15;
        int jj = w * 16 + rr;
        if (jj < 150) {
            int srow = g * 150 + jj;
            if (mode[j] == 1) {
                if (c < 300) v = pa.s[j][srow * 300 + c];
                else if (c == 300) v = pa.bb[j - 3][srow];  // bias via A col 300 == 1.0
            } else {
                if (c < 150) v = pa.s[j][srow * 150 + c];
            }
        }
    }
    pa.d[j][idx] = (f16)v;
}

// K0b: exclusive prefix sum of lengths -> compact row offsets
__global__ __launch_bounds__(1024) void scan_k(const int* __restrict__ len, int* __restrict__ coff) {
    __shared__ int a[1024];
    int t = threadIdx.x;
    a[t] = len[t];
    __syncthreads();
    for (int off = 1; off < 1024; off <<= 1) {
        int v = (t >= off) ? a[t - off] : 0;
        __syncthreads();
        a[t] += v;
        __syncthreads();
    }
    coff[t] = a[t] - len[t];
}

// ---------------------------------------------------------------------------
// Dual-B NT GEMM (f16 out): blockIdx.y selects {B0,bias0,C0} (y<2) or
// {B1,bias1,C1}; n0=(y&1)*320. M-tile 128 = one sentence when COMPACT.
// ---------------------------------------------------------------------------
template <bool COMPACT>
__global__ __launch_bounds__(256, 2) void gemm2_nt(
    const float* __restrict__ A, int lda, int Keff, int Ksteps,
    const f16* __restrict__ B0, const float* __restrict__ bias0, f16* __restrict__ C0,
    const f16* __restrict__ B1, const float* __restrict__ bias1, f16* __restrict__ C1,
    int ldc, const int* __restrict__ len, const int* __restrict__ coff) {
    __shared__ f16 As[128][40];
    __shared__ f16 Bs[320][40];

    const int tid = threadIdx.x;
    const int m0 = blockIdx.x * 128;
    const int sel = blockIdx.y >> 1;
    const int n0 = (blockIdx.y & 1) * 320;
    const f16* B = sel ? B1 : B0;
    const float* bias = sel ? bias1 : bias0;
    f16* Ch = sel ? C1 : C0;
    const int ldb = Ksteps * 32;
    const int wv = tid >> 6, ln = tid & 63;
    const int lq = ln >> 4, lr = ln & 15;

    int ln_ = 0x7fffffff, co = 0;
    if (COMPACT) { int sn = blockIdx.x; ln_ = len[sn]; co = coff[sn]; }
    const bool act = !COMPACT || (wv * 32 < ln_);

    floatx4 acc[2][20];
#pragma unroll
    for (int s = 0; s < 2; ++s)
#pragma unroll
        for (int nt = 0; nt < 20; ++nt) acc[s][nt] = 0;

    for (int kt = 0; kt < Ksteps; ++kt) {
        {
            int r = tid >> 1, c0 = (tid & 1) * 16;
            if (!COMPACT || r < ln_) {
                int gk = kt * 32 + c0;
                const float* ap = A + (size_t)(m0 + r) * lda + gk;
                float v[16];
                if (gk + 16 <= Keff) {
                    const float4* p4 = (const float4*)ap;
                    float4 a0 = p4[0], a1 = p4[1], a2 = p4[2], a3 = p4[3];
                    v[0]=a0.x; v[1]=a0.y; v[2]=a0.z; v[3]=a0.w;
                    v[4]=a1.x; v[5]=a1.y; v[6]=a1.z; v[7]=a1.w;
                    v[8]=a2.x; v[9]=a2.y; v[10]=a2.z; v[11]=a2.w;
                    v[12]=a3.x; v[13]=a3.y; v[14]=a3.z; v[15]=a3.w;
                } else {
#pragma unroll
                    for (int j = 0; j < 16; ++j) v[j] = (gk + j < Keff) ? ap[j] : 0.0f;
                }
                half8 h0, h1;
#pragma unroll
                for (int j = 0; j < 8; ++j) { h0[j] = (f16)v[j]; h1[j] = (f16)v[8 + j]; }
                *(half8*)&As[r][c0] = h0;
                *(half8*)&As[r][c0 + 8] = h1;
            }
        }
        {
            int q = tid & 3;
#pragma unroll
            for (int i = 0; i < 5; ++i) {
                int rb = (tid >> 2) + i * 64;
                half8 bv = *(const half8*)(B + (size_t)(n0 + rb) * ldb + kt * 32 + q * 8);
                *(half8*)&Bs[rb][q * 8] = bv;
            }
        }
        __syncthreads();
        if (act) {
            half8 af0 = *(const half8*)&As[wv * 32 + lr][lq * 8];
            half8 af1 = *(const half8*)&As[wv * 32 + 16 + lr][lq * 8];
#pragma unroll
            for (int nt = 0; nt < 20; ++nt) {
                half8 bf = *(const half8*)&Bs[nt * 16 + lr][lq * 8];
                acc[0][nt] = MFMA16(af0, bf, acc[0][nt]);
                acc[1][nt] = MFMA16(af1, bf, acc[1][nt]);
            }
        }
        __syncthreads();
    }
    if (!act) return;
#pragma unroll
    for (int s = 0; s < 2; ++s)
#pragma unroll
        for (int nt = 0; nt < 20; ++nt)
#pragma unroll
            for (int rr = 0; rr < 4; ++rr) {
                int t = wv * 32 + s * 16 + lq * 4 + rr;
                int col = n0 + nt * 16 + lr;
                float v = acc[s][nt][rr];
                if (bias && col < 600) v += bias[col];
                if (COMPACT) {
                    if (t < ln_) Ch[(size_t)(co + t) * ldc + col] = (f16)v;
                } else {
                    Ch[(size_t)(m0 + t) * ldc + col] = (f16)v;
                }
            }
}

// ---------------------------------------------------------------------------
// Single-output NT GEMM fp32 out + bias + relu (MLP stage only)
// ---------------------------------------------------------------------------
__global__ __launch_bounds__(256, 2) void gemm_mlp(
    const float* __restrict__ A, int lda, int Ksteps,
    const f16* __restrict__ B, const float* __restrict__ bias,
    float* __restrict__ Cf, int ldc) {
    __shared__ f16 As[128][40];
    __shared__ f16 Bs[320][40];
    const int tid = threadIdx.x;
    const int m0 = blockIdx.x * 128;
    const int ldb = Ksteps * 32;
    const int wv = tid >> 6, ln = tid & 63;
    const int lq = ln >> 4, lr = ln & 15;

    floatx4 acc[2][20];
#pragma unroll
    for (int s = 0; s < 2; ++s)
#pragma unroll
        for (int nt = 0; nt < 20; ++nt) acc[s][nt] = 0;

    for (int kt = 0; kt < Ksteps; ++kt) {
        {
            int r = tid >> 1, c0 = (tid & 1) * 16;
            const float4* p4 = (const float4*)(A + (size_t)(m0 + r) * lda + kt * 32 + c0);
            float4 a0 = p4[0], a1 = p4[1], a2 = p4[2], a3 = p4[3];
            half8 h0, h1;
            h0[0]=(f16)a0.x; h0[1]=(f16)a0.y; h0[2]=(f16)a0.z; h0[3]=(f16)a0.w;
            h0[4]=(f16)a1.x; h0[5]=(f16)a1.y; h0[6]=(f16)a1.z; h0[7]=(f16)a1.w;
            h1[0]=(f16)a2.x; h1[1]=(f16)a2.y; h1[2]=(f16)a2.z; h1[3]=(f16)a2.w;
            h1[4]=(f16)a3.x; h1[5]=(f16)a3.y; h1[6]=(f16)a3.z; h1[7]=(f16)a3.w;
            *(half8*)&As[r][c0] = h0;
            *(half8*)&As[r][c0 + 8] = h1;
        }
        {
            int q = tid & 3;
#pragma unroll
            for (int i = 0; i < 5; ++i) {
                int rb = (tid >> 2) + i * 64;
                half8 bv = *(const half8*)(B + (size_t)rb * ldb + kt * 32 + q * 8);
                *(half8*)&Bs[rb][q * 8] = bv;
            }
        }
        __syncthreads();
        half8 af0 = *(const half8*)&As[wv * 32 + lr][lq * 8];
        half8 af1 = *(const half8*)&As[wv * 32 + 16 + lr][lq * 8];
#pragma unroll
        for (int nt = 0; nt < 20; ++nt) {
            half8 bf = *(const half8*)&Bs[nt * 16 + lr][lq * 8];
            acc[0][nt] = MFMA16(af0, bf, acc[0][nt]);
            acc[1][nt] = MFMA16(af1, bf, acc[1][nt]);
        }
        __syncthreads();
    }
#pragma unroll
    for (int s = 0; s < 2; ++s)
#pragma unroll
        for (int nt = 0; nt < 20; ++nt)
#pragma unroll
            for (int rr = 0; rr < 4; ++rr) {
                int t = wv * 32 + s * 16 + lq * 4 + rr;
                int col = nt * 16 + lr;
                float v = acc[s][nt][rr];
                if (col < 300) v += bias[col];   // b_mlp has 300 entries
                v = fmaxf(v, 0.0f);
                Cf[(size_t)(m0 + t) * ldc + col] = v;
            }
}

// ---------------------------------------------------------------------------
// K2: LSTM1 recurrence, 16 sentences/WG. Xg prefetched into registers,
// dual-accumulator MFMA chains, w_hh register-resident B-fragments.
// ---------------------------------------------------------------------------
__global__ __launch_bounds__(512, 2) void lstm1_k(
    const f16* __restrict__ XgF, const f16* __restrict__ XgB,
    const f16* __restrict__ WhF, const f16* __restrict__ WhB,
    float* __restrict__ sent,
    const int* __restrict__ len, const int* __restrict__ coff, int dirbase) {
    const int dir = dirbase + blockIdx.y;
    const f16* Xg = dir ? XgB : XgF;
    const f16* Whh = dir ? WhB : WhF;
    __shared__ float gates[16][644];
    __shared__ f16 hbuf[16][168];
    __shared__ float cbuf[16][153];
    __shared__ float pool[16][153];
    __shared__ int lens_s[16], coff_s[16];

    const int tid = threadIdx.x;
    const int wv = tid >> 6, ln = tid & 63;
    const int lq = ln >> 4, lr = ln & 15;
    const int sb = blockIdx.x * 16;

    if (tid < 16) { lens_s[tid] = len[sb + tid]; coff_s[tid] = coff[sb + tid]; }
    for (int i = tid; i < 16 * 168; i += 512) (&hbuf[0][0])[i] = (f16)0.0f;
    for (int i = tid; i < 16 * 153; i += 512) { (&cbuf[0][0])[i] = 0.0f; (&pool[0][0])[i] = -1e30f; }
    __syncthreads();

    int maxlen = 0;
#pragma unroll
    for (int j = 0; j < 16; ++j) maxlen = max(maxlen, lens_s[j]);

    const int nb = wv * 80;
    half8 bf[5][5];
#pragma unroll
    for (int nt = 0; nt < 5; ++nt)
#pragma unroll
        for (int kt = 0; kt < 5; ++kt)
            bf[nt][kt] = *(const half8*)(Whh + (size_t)(nb + nt * 16 + lr) * 160 + kt * 32 + lq * 8);

    half8 af[5];
#pragma unroll
    for (int kt = 0; kt < 5; ++kt) af[kt] = *(const half8*)&hbuf[lr][kt * 32 + lq * 8];

    f16 xpre[5][4];
#pragma unroll
    for (int nt = 0; nt < 5; ++nt)
#pragma unroll
        for (int rr = 0; rr < 4; ++rr) {
            int m = lq * 4 + rr;
            int te = dir ? max(lens_s[m] - 1, 0) : 0;
            xpre[nt][rr] = Xg[(size_t)(coff_s[m] + te) * 640 + nb + nt * 16 + lr];
        }

    for (int t = 0; t < maxlen; ++t) {
#pragma unroll
        for (int nt = 0; nt < 5; ++nt) {
            int col = nb + nt * 16 + lr;
            floatx4 a0, a1;
#pragma unroll
            for (int rr = 0; rr < 4; ++rr) { a0[rr] = (float)xpre[nt][rr]; a1[rr] = 0.0f; }
            a0 = MFMA16(af[0], bf[nt][0], a0);
            a1 = MFMA16(af[1], bf[nt][1], a1);
            a0 = MFMA16(af[2], bf[nt][2], a0);
            a1 = MFMA16(af[3], bf[nt][3], a1);
            a0 = MFMA16(af[4], bf[nt][4], a0);
#pragma unroll
            for (int rr = 0; rr < 4; ++rr) gates[lq * 4 + rr][col] = a0[rr] + a1[rr];
        }
#pragma unroll
        for (int nt = 0; nt < 5; ++nt)
#pragma unroll
            for (int rr = 0; rr < 4; ++rr) {
                int m = lq * 4 + rr;
                int te = dir ? max(lens_s[m] - 2 - t, 0) : min(t + 1, lens_s[m] - 1);
                xpre[nt][rr] = Xg[(size_t)(coff_s[m] + te) * 640 + nb + nt * 16 + lr];
            }
        __syncthreads();
        for (int idx = tid; idx < 2400; idx += 512) {
            int j = idx >> 4, m = idx & 15;
            float gi = gates[m][j], gf = gates[m][150 + j];
            float gg = gates[m][300 + j], go = gates[m][450 + j];
            float cn = sigm_(gf) * cbuf[m][j] + sigm_(gi) * tanh_(gg);
            float hn = sigm_(go) * tanh_(cn);
            cbuf[m][j] = cn;
            hbuf[m][j] = (f16)hn;
            if (t < lens_s[m]) pool[m][j] = fmaxf(pool[m][j], hn);
        }
        __syncthreads();
#pragma unroll
        for (int kt = 0; kt < 5; ++kt) af[kt] = *(const half8*)&hbuf[lr][kt * 32 + lq * 8];
    }
    for (int idx = tid; idx < 2400; idx += 512) {
        int j = idx >> 4, m = idx & 15;
        sent[(size_t)(sb + m) * 300 + (dir ? 150 : 0) + j] = pool[m][j];
    }
}

// ---------------------------------------------------------------------------
// K4a: per sentence: ex softmax(7), ex_pre argmax, avg_lab, build A2 fp32
// ---------------------------------------------------------------------------
__global__ void k4a(const float* __restrict__ sent, const float* __restrict__ w_ex,
                    const float* __restrict__ b_ex, const float* __restrict__ lab,
                    float* __restrict__ A2, int* __restrict__ expre) {
    int n = blockIdx.x, l = threadIdx.x;
    float s[5];
#pragma unroll
    for (int i = 0; i < 5; ++i) { int d = l + 64 * i; s[i] = (d < 300) ? sent[(size_t)n * 300 + d] : 0.0f; }
    float logit[7];
#pragma unroll
    for (int c = 0; c < 7; ++c) {
        float p = 0.0f;
#pragma unroll
        for (int i = 0; i < 5; ++i) { int d = l + 64 * i; if (d < 300) p += s[i] * w_ex[c * 300 + d]; }
#pragma unroll
        for (int off = 32; off > 0; off >>= 1) p += __shfl_xor(p, off);
        logit[c] = p + b_ex[c];
    }
    float mx = logit[0];
#pragma unroll
    for (int c = 1; c < 7; ++c) mx = fmaxf(mx, logit[c]);
    float e[7], ssum = 0.0f;
#pragma unroll
    for (int c = 0; c < 7; ++c) { e[c] = ex2_(LOG2E * (logit[c] - mx)); ssum += e[c]; }
    int best = 0;
#pragma unroll
    for (int c = 1; c < 7; ++c) if (logit[c] > logit[best]) best = c;
    if (l == 0) expre[n] = best;
    float inv = rcp_(ssum);
#pragma unroll
    for (int i = 0; i < 5; ++i) {
        int d = l + 64 * i;
        if (d < 300) {
            float al = 0.0f;
#pragma unroll
            for (int c = 0; c < 7; ++c) al += e[c] * inv * lab[c * 300 + d];
            A2[(size_t)n * 640 + d] = s[i];
            A2[(size_t)n * 640 + 300 + d] = al;
        }
    }
    if (l < 40) A2[(size_t)n * 640 + 600 + l] = 0.0f;
}

// ---------------------------------------------------------------------------
// K5: score softmax over N, exact top-512, penalty partial, mixed build.
// mixed col 300 = 1.0 (bias via folded weight row); zeroes dout[1024].
// ---------------------------------------------------------------------------
__global__ __launch_bounds__(1024) void k5(const float* __restrict__ joint,
                                           const float* __restrict__ sent,
                                           const float* __restrict__ w_sc,
                                           const float* __restrict__ b_sc,
                                           const int* __restrict__ gold,
                                           const int* __restrict__ expre,
                                           float* __restrict__ mixed,
                                           float* __restrict__ pen_out,
                                           float* __restrict__ dout) {
    __shared__ float arr[1024];
    __shared__ float red[1024];
    int n = threadIdx.x;
    const float4* jr = (const float4*)(joint + (size_t)n * 320);
    const float4* wr = (const float4*)w_sc;
    float sc = b_sc[0];
    for (int q = 0; q < 75; ++q) {
        float4 a = jr[q], w = wr[q];
        sc += a.x * w.x + a.y * w.y + a.z * w.z + a.w * w.w;
    }
    float sg = sigm_(sc);
    arr[n] = sg;
    red[n] = sg;
    __syncthreads();
    for (int s = 512; s > 0; s >>= 1) { if (n < s) red[n] = fmaxf(red[n], red[n + s]); __syncthreads(); }
    float mx = red[0];
    __syncthreads();
    float ex = ex2_(LOG2E * (sg - mx));
    red[n] = ex;
    __syncthreads();
    for (int s = 512; s > 0; s >>= 1) { if (n < s) red[n] += red[n + s]; __syncthreads(); }
    float score = ex * rcp_(red[0]);
    __syncthreads();
    int cnt = 0;
    for (int j = 0; j < 1024; ++j) {
        float vj = arr[j];
        cnt += (vj > sg) || (vj == sg && j < n);
    }
    bool top = cnt < 512;
    bool wrong = gold[n] != expre[n];
    float contrib = wrong ? (top ? 1.5f * score : 0.0f) : (top ? 0.0f : -1.5f * score);
    red[n] = contrib;
    __syncthreads();
    for (int s = 512; s > 0; s >>= 1) { if (n < s) red[n] += red[n + s]; __syncthreads(); }
    if (n == 0) { pen_out[0] = red[0]; dout[1024] = 0.0f; }
    const float4* sr = (const float4*)(sent + (size_t)n * 300);
    float4* mr = (float4*)(mixed + (size_t)n * 320);
    for (int q = 0; q < 75; ++q) mr[q] = top ? jr[q] : sr[q];
    float4 one = {1.0f, 0.0f, 0.0f, 0.0f};
    mr[75] = one;
    float4 z = {0, 0, 0, 0};
    for (int q = 76; q < 80; ++q) mr[q] = z;
}

// ---------------------------------------------------------------------------
// K7: LSTM2, batch=1, 1024 steps, 2 WGs. Gate-interleaved weights: wave w,
// lane lr holds ALL 4 gates of element j=w*16+lr in registers after MFMA ->
// elementwise fully in-reg, no gate LDS. Double-buffered h (320 B), one
// barrier/step. G2 row prefetched one step ahead; bias pre-folded into G2.
// ---------------------------------------------------------------------------
__global__ __launch_bounds__(640, 1) void lstm2_k(
    const f16* __restrict__ G2f, const f16* __restrict__ G2b,
    const f16* __restrict__ H2f, const f16* __restrict__ H2b,
    float* __restrict__ out2) {
    const int dir = blockIdx.x;
    const f16* G2 = dir ? G2b : G2f;    // [1024][640] gate-interleaved cols
    const f16* Whh = dir ? H2b : H2f;   // [640][160] gate-interleaved rows
    __shared__ f16 hl[2][160];

    const int tid = threadIdx.x;
    const int wv = tid >> 6, ln = tid & 63;
    const int lq = ln >> 4, lr = ln & 15;
    const int jme = wv * 16 + lr;       // h element this lane owns (if <150)
    for (int i = tid; i < 320; i += 640) ((f16*)hl)[i] = (f16)0.0f;
    __syncthreads();

    float c = 0.0f;                     // replicated across the 4 quads

    half8 bf[4][5];
#pragma unroll
    for (int g = 0; g < 4; ++g)
#pragma unroll
        for (int kt = 0; kt < 5; ++kt)
            bf[g][kt] = *(const half8*)(Whh + (size_t)(wv * 64 + g * 16 + lr) * 160 + kt * 32 + lq * 8);

    f16 gpre[4];
    {
        int r0 = dir ? 1023 : 0;
#pragma unroll
        for (int g = 0; g < 4; ++g) gpre[g] = G2[(size_t)r0 * 640 + wv * 64 + g * 16 + lr];
    }

    for (int step = 0; step < 1024; ++step) {
        const int row = dir ? (1023 - step) : step;
        const int p = step & 1;
        half8 af[5];
#pragma unroll
        for (int kt = 0; kt < 5; ++kt) af[kt] = *(const half8*)&hl[p][kt * 32 + lq * 8];
        float gate[4];
#pragma unroll
        for (int g = 0; g < 4; ++g) {
            float g0 = (float)gpre[g];
            floatx4 a0 = {g0, g0, g0, g0};
            floatx4 a1 = {0, 0, 0, 0};
            a0 = MFMA16(af[0], bf[g][0], a0);
            a1 = MFMA16(af[1], bf[g][1], a1);
            a0 = MFMA16(af[2], bf[g][2], a0);
            a1 = MFMA16(af[3], bf[g][3], a1);
            a0 = MFMA16(af[4], bf[g][4], a0);
            gate[g] = a0[0] + a1[0];    // all C rows identical; row 0
        }
        {
            int nr = dir ? max(1022 - step, 0) : min(step + 1, 1023);
#pragma unroll
            for (int g = 0; g < 4; ++g) gpre[g] = G2[(size_t)nr * 640 + wv * 64 + g * 16 + lr];
        }
        // in-register elementwise (gates i,f,g,o = gate[0..3])
        float cn = sigm_(gate[1]) * c + sigm_(gate[0]) * tanh_(gate[2]);
        float hn = sigm_(gate[3]) * tanh_(cn);
        c = cn;
        if (lq == 0 && jme < 150) {
            hl[p ^ 1][jme] = (f16)hn;
            out2[(size_t)row * 300 + dir * 150 + jme] = hn;
        }
        __syncthreads();
    }
}

// ---------------------------------------------------------------------------
// K8: tag logits, log_softmax, argmax -> d_out[0..1023]; CE partial + pen
// atomically into d_out[1024] (zeroed by k5). 8 blocks x 256, w_tag in LDS.
// ---------------------------------------------------------------------------
__global__ __launch_bounds__(256) void k8(const float* __restrict__ out2,
                                          const float* __restrict__ w_tag,
                                          const float* __restrict__ b_tag,
                                          const int* __restrict__ gold,
                                          const float* __restrict__ pen,
                                          float* __restrict__ dout) {
    __shared__ float wt[7][304];
    __shared__ float red[128];
    const int tid = threadIdx.x;
    for (int i = tid; i < 2100; i += 256) wt[i / 300][i % 300] = w_tag[i];
    __syncthreads();
    float ce = 0.0f;
    if (tid < 128) {
        int n = blockIdx.x * 128 + tid;
        float lg[7];
#pragma unroll
        for (int c = 0; c < 7; ++c) lg[c] = b_tag[c];
        const float4* orow = (const float4*)(out2 + (size_t)n * 300);
        for (int q = 0; q < 75; ++q) {
            float4 v = orow[q];
#pragma unroll
            for (int c = 0; c < 7; ++c)
                lg[c] += v.x * wt[c][q * 4] + v.y * wt[c][q * 4 + 1] +
                         v.z * wt[c][q * 4 + 2] + v.w * wt[c][q * 4 + 3];
        }
        float mx = lg[0];
#pragma unroll
        for (int c = 1; c < 7; ++c) mx = fmaxf(mx, lg[c]);
        float se = 0.0f;
#pragma unroll
        for (int c = 0; c < 7; ++c) se += ex2_(LOG2E * (lg[c] - mx));
        float lse = logf(se);
        int best = 0;
#pragma unroll
        for (int c = 1; c < 7; ++c) if (lg[c] > lg[best]) best = c;
        dout[n] = (float)best;
        ce = -(lg[gold[n]] - mx - lse);
    }
    if (tid < 128) red[tid] = ce;
    __syncthreads();
    for (int s = 64; s > 0; s >>= 1) { if (tid < s) red[tid] += red[tid + s]; __syncthreads(); }
    if (tid == 0) atomicAdd(&dout[1024], red[0] + (blockIdx.x == 0 ? pen[0] : 0.0f));
}

// ---------------------------------------------------------------------------
extern "C" void kernel_launch(void* const* d_in, const int* in_sizes, int n_in,
                              void* d_out, int out_size, void* d_ws, size_t ws_size,
                              hipStream_t stream) {
    const float* x       = (const float*)d_in[0];
    const int*   lengths = (const int*)d_in[1];
    const int*   gold    = (const int*)d_in[2];
    const float* w1f_ih  = (const float*)d_in[3];
    const float* w1f_hh  = (const float*)d_in[4];
    const float* b1f     = (const float*)d_in[5];
    const float* w1b_ih  = (const float*)d_in[6];
    const float* w1b_hh  = (const float*)d_in[7];
    const float* b1b     = (const float*)d_in[8];
    const float* lab     = (const float*)d_in[9];
    const float* w_ex    = (const float*)d_in[10];
    const float* b_ex    = (const float*)d_in[11];
    const float* w_mlp   = (const float*)d_in[12];
    const float* b_mlp   = (const float*)d_in[13];
    const float* w_sc    = (const float*)d_in[14];
    const float* b_sc    = (const float*)d_in[15];
    const float* w2f_ih  = (const float*)d_in[16];
    const float* w2f_hh  = (const float*)d_in[17];
    const float* b2f     = (const float*)d_in[18];
    const float* w2b_ih  = (const float*)d_in[19];
    const float* w2b_hh  = (const float*)d_in[20];
    const float* b2b     = (const float*)d_in[21];
    const float* w_tag   = (const float*)d_in[22];
    const float* b_tag   = (const float*)d_in[23];
    float* dout = (float*)d_out;
    char* ws = (char*)d_ws;

    size_t o = 0;
    auto alloc = [&](size_t bytes) { size_t r = o; o += (bytes + 255) & ~(size_t)255; return r; };
    size_t W1F  = alloc(640 * 320 * 2);
    size_t W1B  = alloc(640 * 320 * 2);
    size_t WMLP = alloc(320 * 640 * 2);
    size_t W2F  = alloc(640 * 320 * 2);
    size_t W2B  = alloc(640 * 320 * 2);
    size_t H1F  = alloc(640 * 160 * 2);
    size_t H1B  = alloc(640 * 160 * 2);
    size_t H2F  = alloc(640 * 160 * 2);
    size_t H2B  = alloc(640 * 160 * 2);
    size_t COFF = alloc(1024 * 4);
    size_t SENT = alloc((size_t)1024 * 300 * 4);
    size_t A2   = alloc((size_t)1024 * 640 * 4);
    size_t EXP  = alloc(1024 * 4);
    size_t JNT  = alloc((size_t)1024 * 320 * 4);
    size_t MIX  = alloc((size_t)1024 * 320 * 4);
    size_t G2F  = alloc((size_t)1024 * 640 * 2);
    size_t G2B  = alloc((size_t)1024 * 640 * 2);
    size_t OUT2 = alloc((size_t)1024 * 300 * 4);
    size_t PEN  = alloc(256);
    const size_t XGSZ = (size_t)131072 * 640 * 2;
    size_t XGF = alloc(XGSZ);
    bool bigws = (o + XGSZ) <= ws_size;
    size_t XGB = bigws ? alloc(XGSZ) : XGF;
    (void)in_sizes; (void)n_in; (void)out_size;

    PackA pa;
    pa.s[0] = w1f_ih; pa.d[0] = (f16*)(ws + W1F);
    pa.s[1] = w1b_ih; pa.d[1] = (f16*)(ws + W1B);
    pa.s[2] = w_mlp;  pa.d[2] = (f16*)(ws + WMLP);
    pa.s[3] = w2f_ih; pa.d[3] = (f16*)(ws + W2F);
    pa.s[4] = w2b_ih; pa.d[4] = (f16*)(ws + W2B);
    pa.s[5] = w1f_hh; pa.d[5] = (f16*)(ws + H1F);
    pa.s[6] = w1b_hh; pa.d[6] = (f16*)(ws + H1B);
    pa.s[7] = w2f_hh; pa.d[7] = (f16*)(ws + H2F);
    pa.s[8] = w2b_hh; pa.d[8] = (f16*)(ws + H2B);
    pa.bb[0] = b2f;   pa.bb[1] = b2b;
    pack_k<<<dim3(800, 9), 256, 0, stream>>>(pa);
    scan_k<<<1, 1024, 0, stream>>>(lengths, (int*)(ws + COFF));

    const int* coffp = (const int*)(ws + COFF);
    if (bigws) {
        gemm2_nt<true><<<dim3(1024, 4), 256, 0, stream>>>(
            x, 300, 300, 10,
            (const f16*)(ws + W1F), b1f, (f16*)(ws + XGF),
            (const f16*)(ws + W1B), b1b, (f16*)(ws + XGB),
            640, lengths, coffp);
        lstm1_k<<<dim3(64, 2), 512, 0, stream>>>(
            (const f16*)(ws + XGF), (const f16*)(ws + XGB),
            (const f16*)(ws + H1F), (const f16*)(ws + H1B),
            (float*)(ws + SENT), lengths, coffp, 0);
    } else {
        gemm2_nt<true><<<dim3(1024, 2), 256, 0, stream>>>(
            x, 300, 300, 10,
            (const f16*)(ws + W1F), b1f, (f16*)(ws + XGF),
            (const f16*)(ws + W1F), b1f, (f16*)(ws + XGF),
            640, lengths, coffp);
        lstm1_k<<<dim3(64, 1), 512, 0, stream>>>(
            (const f16*)(ws + XGF), (const f16*)(ws + XGF),
            (const f16*)(ws + H1F), (const f16*)(ws + H1F),
            (float*)(ws + SENT), lengths, coffp, 0);
        gemm2_nt<true><<<dim3(1024, 2), 256, 0, stream>>>(
            x, 300, 300, 10,
            (const f16*)(ws + W1B), b1b, (f16*)(ws + XGF),
            (const f16*)(ws + W1B), b1b, (f16*)(ws + XGF),
            640, lengths, coffp);
        lstm1_k<<<dim3(64, 1), 512, 0, stream>>>(
            (const f16*)(ws + XGF), (const f16*)(ws + XGF),
            (const f16*)(ws + H1B), (const f16*)(ws + H1B),
            (float*)(ws + SENT), lengths, coffp, 1);
    }

    k4a<<<1024, 64, 0, stream>>>((const float*)(ws + SENT), w_ex, b_ex, lab,
                                 (float*)(ws + A2), (int*)(ws + EXP));
    gemm_mlp<<<8, 256, 0, stream>>>((const float*)(ws + A2), 640, 20,
                                    (const f16*)(ws + WMLP), b_mlp,
                                    (float*)(ws + JNT), 320);
    k5<<<1, 1024, 0, stream>>>((const float*)(ws + JNT), (const float*)(ws + SENT),
                               w_sc, b_sc, gold, (const int*)(ws + EXP),
                               (float*)(ws + MIX), (float*)(ws + PEN), dout);

    // LSTM2 input gates: bias folded via MIX col 300 == 1.0 (no bias arg)
    gemm2_nt<false><<<dim3(8, 4), 256, 0, stream>>>(
        (const float*)(ws + MIX), 320, 320, 10,
        (const f16*)(ws + W2F), nullptr, (f16*)(ws + G2F),
        (const f16*)(ws + W2B), nullptr, (f16*)(ws + G2B),
        640, nullptr, nullptr);
    lstm2_k<<<2, 640, 0, stream>>>((const f16*)(ws + G2F), (const f16*)(ws + G2B),
                                   (const f16*)(ws + H2F), (const f16*)(ws + H2B),
                                   (float*)(ws + OUT2));

    k8<<<8, 256, 0, stream>>>((const float*)(ws + OUT2), w_tag, b_tag, gold,
                              (const float*)(ws + PEN), dout);
}

// Round 4
// 1933.886 us; speedup vs baseline: 1.7497x; 1.0000x over previous
//
#include <hip/hip_runtime.h>

// ---------------------------------------------------------------------------
// MyModel: BiLSTM1(token) + maxpool -> softmax7/avg_lab -> MLP -> top-k gate
//          -> BiLSTM2(sentence seq, batch=1) -> log_softmax CE + penalty
// N=1024, L=128, D=300, H=150, G=4H=600
// ---------------------------------------------------------------------------

typedef _Float16 f16;
typedef _Float16 half8 __attribute__((ext_vector_type(8)));
typedef float    floatx4 __attribute__((ext_vector_type(4)));

#define MFMA16(a, b, c) __builtin_amdgcn_mfma_f32_16x16x32_f16((a), (b), (c), 0, 0, 0)
#define LOG2E 1.44269504f

__device__ __forceinline__ float rcp_(float x) { return __builtin_amdgcn_rcpf(x); }
__device__ __forceinline__ float ex2_(float x) { return __builtin_amdgcn_exp2f(x); }
__device__ __forceinline__ float sigm_(float x) { return rcp_(1.0f + ex2_(-LOG2E * x)); }
__device__ __forceinline__ float tanh_(float x) { return 1.0f - 2.0f * rcp_(1.0f + ex2_(2.0f * LOG2E * x)); }

// LDS-only barrier (CK block_sync_lds pattern): waits LDS ops, does NOT drain
// vmcnt -> global prefetch loads / stores stay in flight across the barrier.
__device__ __forceinline__ void bar_lds() {
    asm volatile("s_waitcnt lgkmcnt(0)" ::: "memory");
    __builtin_amdgcn_s_barrier();
}

// ---------------------------------------------------------------------------
// K0a: pack fp32 weights into zero-padded f16 buffers.
// mode 0: plain pad.  mode 1: LSTM2 input weights, gate-interleaved rows
// (row r=w*64+g*16+rr -> src gate g, j=w*16+rr) + bias folded at col 300.
// mode 2: LSTM2 recurrent weights, same row interleave.
// ---------------------------------------------------------------------------
struct PackA { const float* s[9]; f16* d[9]; const float* bb[2]; };

__global__ void pack_k(PackA pa) {
    const int R[9]    = {640, 640, 320, 640, 640, 640, 640, 640, 640};
    const int C[9]    = {320, 320, 640, 320, 320, 160, 160, 160, 160};
    const int rows[9] = {600, 600, 300, 600, 600, 600, 600, 600, 600};
    const int cols[9] = {300, 300, 600, 300, 300, 150, 150, 150, 150};
    const int mode[9] = {0, 0, 0, 1, 1, 0, 0, 2, 2};
    int j = blockIdx.y;
    int idx = blockIdx.x * 256 + threadIdx.x;
    int RC = R[j] * C[j];
    if (idx >= RC) return;
    int r = idx / C[j], c = idx % C[j];
    float v = 0.0f;
    if (mode[j] == 0) {
        if (r < rows[j] && c < cols[j]) v = pa.s[j][r * cols[j] + c];
    } else {
        int w = r >> 6, g = (r >> 4) & 3, rr = r & 15;
        int jj = w * 16 + rr;
        if (jj < 150) {
            int srow = g * 150 + jj;
            if (mode[j] == 1) {
                if (c < 300) v = pa.s[j][srow * 300 + c];
                else if (c == 300) v = pa.bb[j - 3][srow];
            } else {
                if (c < 150) v = pa.s[j][srow * 150 + c];
            }
        }
    }
    pa.d[j][idx] = (f16)v;
}

// K0b: exclusive prefix sum of lengths -> compact row offsets
__global__ __launch_bounds__(1024) void scan_k(const int* __restrict__ len, int* __restrict__ coff) {
    __shared__ int a[1024];
    int t = threadIdx.x;
    a[t] = len[t];
    __syncthreads();
    for (int off = 1; off < 1024; off <<= 1) {
        int v = (t >= off) ? a[t - off] : 0;
        __syncthreads();
        a[t] += v;
        __syncthreads();
    }
    coff[t] = a[t] - len[t];
}

// ---------------------------------------------------------------------------
// Dual-B NT GEMM (f16 out): blockIdx.y selects {B0,bias0,C0} (y<2) or
// {B1,bias1,C1}; n0=(y&1)*320. M-tile 128 = one sentence when COMPACT.
// ---------------------------------------------------------------------------
template <bool COMPACT>
__global__ __launch_bounds__(256, 2) void gemm2_nt(
    const float* __restrict__ A, int lda, int Keff, int Ksteps,
    const f16* __restrict__ B0, const float* __restrict__ bias0, f16* __restrict__ C0,
    const f16* __restrict__ B1, const float* __restrict__ bias1, f16* __restrict__ C1,
    int ldc, const int* __restrict__ len, const int* __restrict__ coff) {
    __shared__ f16 As[128][40];
    __shared__ f16 Bs[320][40];

    const int tid = threadIdx.x;
    const int m0 = blockIdx.x * 128;
    const int sel = blockIdx.y >> 1;
    const int n0 = (blockIdx.y & 1) * 320;
    const f16* B = sel ? B1 : B0;
    const float* bias = sel ? bias1 : bias0;
    f16* Ch = sel ? C1 : C0;
    const int ldb = Ksteps * 32;
    const int wv = tid >> 6, ln = tid & 63;
    const int lq = ln >> 4, lr = ln & 15;

    int ln_ = 0x7fffffff, co = 0;
    if (COMPACT) { int sn = blockIdx.x; ln_ = len[sn]; co = coff[sn]; }
    const bool act = !COMPACT || (wv * 32 < ln_);

    floatx4 acc[2][20];
#pragma unroll
    for (int s = 0; s < 2; ++s)
#pragma unroll
        for (int nt = 0; nt < 20; ++nt) acc[s][nt] = 0;

    for (int kt = 0; kt < Ksteps; ++kt) {
        {
            int r = tid >> 1, c0 = (tid & 1) * 16;
            if (!COMPACT || r < ln_) {
                int gk = kt * 32 + c0;
                const float* ap = A + (size_t)(m0 + r) * lda + gk;
                float v[16];
                if (gk + 16 <= Keff) {
                    const float4* p4 = (const float4*)ap;
                    float4 a0 = p4[0], a1 = p4[1], a2 = p4[2], a3 = p4[3];
                    v[0]=a0.x; v[1]=a0.y; v[2]=a0.z; v[3]=a0.w;
                    v[4]=a1.x; v[5]=a1.y; v[6]=a1.z; v[7]=a1.w;
                    v[8]=a2.x; v[9]=a2.y; v[10]=a2.z; v[11]=a2.w;
                    v[12]=a3.x; v[13]=a3.y; v[14]=a3.z; v[15]=a3.w;
                } else {
#pragma unroll
                    for (int j = 0; j < 16; ++j) v[j] = (gk + j < Keff) ? ap[j] : 0.0f;
                }
                half8 h0, h1;
#pragma unroll
                for (int j = 0; j < 8; ++j) { h0[j] = (f16)v[j]; h1[j] = (f16)v[8 + j]; }
                *(half8*)&As[r][c0] = h0;
                *(half8*)&As[r][c0 + 8] = h1;
            }
        }
        {
            int q = tid & 3;
#pragma unroll
            for (int i = 0; i < 5; ++i) {
                int rb = (tid >> 2) + i * 64;
                half8 bv = *(const half8*)(B + (size_t)(n0 + rb) * ldb + kt * 32 + q * 8);
                *(half8*)&Bs[rb][q * 8] = bv;
            }
        }
        bar_lds();
        if (act) {
            half8 af0 = *(const half8*)&As[wv * 32 + lr][lq * 8];
            half8 af1 = *(const half8*)&As[wv * 32 + 16 + lr][lq * 8];
#pragma unroll
            for (int nt = 0; nt < 20; ++nt) {
                half8 bf = *(const half8*)&Bs[nt * 16 + lr][lq * 8];
                acc[0][nt] = MFMA16(af0, bf, acc[0][nt]);
                acc[1][nt] = MFMA16(af1, bf, acc[1][nt]);
            }
        }
        bar_lds();
    }
    if (!act) return;
#pragma unroll
    for (int s = 0; s < 2; ++s)
#pragma unroll
        for (int nt = 0; nt < 20; ++nt)
#pragma unroll
            for (int rr = 0; rr < 4; ++rr) {
                int t = wv * 32 + s * 16 + lq * 4 + rr;
                int col = n0 + nt * 16 + lr;
                float v = acc[s][nt][rr];
                if (bias && col < 600) v += bias[col];
                if (COMPACT) {
                    if (t < ln_) Ch[(size_t)(co + t) * ldc + col] = (f16)v;
                } else {
                    Ch[(size_t)(m0 + t) * ldc + col] = (f16)v;
                }
            }
}

// ---------------------------------------------------------------------------
// Single-output NT GEMM fp32 out + bias + relu (MLP stage only)
// ---------------------------------------------------------------------------
__global__ __launch_bounds__(256, 2) void gemm_mlp(
    const float* __restrict__ A, int lda, int Ksteps,
    const f16* __restrict__ B, const float* __restrict__ bias,
    float* __restrict__ Cf, int ldc) {
    __shared__ f16 As[128][40];
    __shared__ f16 Bs[320][40];
    const int tid = threadIdx.x;
    const int m0 = blockIdx.x * 128;
    const int ldb = Ksteps * 32;
    const int wv = tid >> 6, ln = tid & 63;
    const int lq = ln >> 4, lr = ln & 15;

    floatx4 acc[2][20];
#pragma unroll
    for (int s = 0; s < 2; ++s)
#pragma unroll
        for (int nt = 0; nt < 20; ++nt) acc[s][nt] = 0;

    for (int kt = 0; kt < Ksteps; ++kt) {
        {
            int r = tid >> 1, c0 = (tid & 1) * 16;
            const float4* p4 = (const float4*)(A + (size_t)(m0 + r) * lda + kt * 32 + c0);
            float4 a0 = p4[0], a1 = p4[1], a2 = p4[2], a3 = p4[3];
            half8 h0, h1;
            h0[0]=(f16)a0.x; h0[1]=(f16)a0.y; h0[2]=(f16)a0.z; h0[3]=(f16)a0.w;
            h0[4]=(f16)a1.x; h0[5]=(f16)a1.y; h0[6]=(f16)a1.z; h0[7]=(f16)a1.w;
            h1[0]=(f16)a2.x; h1[1]=(f16)a2.y; h1[2]=(f16)a2.z; h1[3]=(f16)a2.w;
            h1[4]=(f16)a3.x; h1[5]=(f16)a3.y; h1[6]=(f16)a3.z; h1[7]=(f16)a3.w;
            *(half8*)&As[r][c0] = h0;
            *(half8*)&As[r][c0 + 8] = h1;
        }
        {
            int q = tid & 3;
#pragma unroll
            for (int i = 0; i < 5; ++i) {
                int rb = (tid >> 2) + i * 64;
                half8 bv = *(const half8*)(B + (size_t)rb * ldb + kt * 32 + q * 8);
                *(half8*)&Bs[rb][q * 8] = bv;
            }
        }
        bar_lds();
        half8 af0 = *(const half8*)&As[wv * 32 + lr][lq * 8];
        half8 af1 = *(const half8*)&As[wv * 32 + 16 + lr][lq * 8];
#pragma unroll
        for (int nt = 0; nt < 20; ++nt) {
            half8 bf = *(const half8*)&Bs[nt * 16 + lr][lq * 8];
            acc[0][nt] = MFMA16(af0, bf, acc[0][nt]);
            acc[1][nt] = MFMA16(af1, bf, acc[1][nt]);
        }
        bar_lds();
    }
#pragma unroll
    for (int s = 0; s < 2; ++s)
#pragma unroll
        for (int nt = 0; nt < 20; ++nt)
#pragma unroll
            for (int rr = 0; rr < 4; ++rr) {
                int t = wv * 32 + s * 16 + lq * 4 + rr;
                int col = nt * 16 + lr;
                float v = acc[s][nt][rr];
                if (col < 300) v += bias[col];
                v = fmaxf(v, 0.0f);
                Cf[(size_t)(m0 + t) * ldc + col] = v;
            }
}

// ---------------------------------------------------------------------------
// K2: LSTM1 recurrence, 16 sentences/WG. Xg prefetched into registers
// (stays in flight across LDS-only barriers), dual-accumulator MFMA chains,
// w_hh register-resident B-fragments.
// ---------------------------------------------------------------------------
__global__ __launch_bounds__(512, 2) void lstm1_k(
    const f16* __restrict__ XgF, const f16* __restrict__ XgB,
    const f16* __restrict__ WhF, const f16* __restrict__ WhB,
    float* __restrict__ sent,
    const int* __restrict__ len, const int* __restrict__ coff, int dirbase) {
    const int dir = dirbase + blockIdx.y;
    const f16* Xg = dir ? XgB : XgF;
    const f16* Whh = dir ? WhB : WhF;
    __shared__ float gates[16][644];
    __shared__ f16 hbuf[16][168];
    __shared__ float cbuf[16][153];
    __shared__ float pool[16][153];
    __shared__ int lens_s[16], coff_s[16];

    const int tid = threadIdx.x;
    const int wv = tid >> 6, ln = tid & 63;
    const int lq = ln >> 4, lr = ln & 15;
    const int sb = blockIdx.x * 16;

    if (tid < 16) { lens_s[tid] = len[sb + tid]; coff_s[tid] = coff[sb + tid]; }
    for (int i = tid; i < 16 * 168; i += 512) (&hbuf[0][0])[i] = (f16)0.0f;
    for (int i = tid; i < 16 * 153; i += 512) { (&cbuf[0][0])[i] = 0.0f; (&pool[0][0])[i] = -1e30f; }
    __syncthreads();

    int maxlen = 0;
#pragma unroll
    for (int j = 0; j < 16; ++j) maxlen = max(maxlen, lens_s[j]);

    const int nb = wv * 80;
    half8 bf[5][5];
#pragma unroll
    for (int nt = 0; nt < 5; ++nt)
#pragma unroll
        for (int kt = 0; kt < 5; ++kt)
            bf[nt][kt] = *(const half8*)(Whh + (size_t)(nb + nt * 16 + lr) * 160 + kt * 32 + lq * 8);

    half8 af[5];
#pragma unroll
    for (int kt = 0; kt < 5; ++kt) af[kt] = *(const half8*)&hbuf[lr][kt * 32 + lq * 8];

    f16 xpre[5][4];
#pragma unroll
    for (int nt = 0; nt < 5; ++nt)
#pragma unroll
        for (int rr = 0; rr < 4; ++rr) {
            int m = lq * 4 + rr;
            int te = dir ? max(lens_s[m] - 1, 0) : 0;
            xpre[nt][rr] = Xg[(size_t)(coff_s[m] + te) * 640 + nb + nt * 16 + lr];
        }

    for (int t = 0; t < maxlen; ++t) {
#pragma unroll
        for (int nt = 0; nt < 5; ++nt) {
            int col = nb + nt * 16 + lr;
            floatx4 a0, a1;
#pragma unroll
            for (int rr = 0; rr < 4; ++rr) { a0[rr] = (float)xpre[nt][rr]; a1[rr] = 0.0f; }
            a0 = MFMA16(af[0], bf[nt][0], a0);
            a1 = MFMA16(af[1], bf[nt][1], a1);
            a0 = MFMA16(af[2], bf[nt][2], a0);
            a1 = MFMA16(af[3], bf[nt][3], a1);
            a0 = MFMA16(af[4], bf[nt][4], a0);
#pragma unroll
            for (int rr = 0; rr < 4; ++rr) gates[lq * 4 + rr][col] = a0[rr] + a1[rr];
        }
#pragma unroll
        for (int nt = 0; nt < 5; ++nt)
#pragma unroll
            for (int rr = 0; rr < 4; ++rr) {
                int m = lq * 4 + rr;
                int te = dir ? max(lens_s[m] - 2 - t, 0) : min(t + 1, lens_s[m] - 1);
                xpre[nt][rr] = Xg[(size_t)(coff_s[m] + te) * 640 + nb + nt * 16 + lr];
            }
        bar_lds();
        for (int idx = tid; idx < 2400; idx += 512) {
            int j = idx >> 4, m = idx & 15;
            float gi = gates[m][j], gf = gates[m][150 + j];
            float gg = gates[m][300 + j], go = gates[m][450 + j];
            float cn = sigm_(gf) * cbuf[m][j] + sigm_(gi) * tanh_(gg);
            float hn = sigm_(go) * tanh_(cn);
            cbuf[m][j] = cn;
            hbuf[m][j] = (f16)hn;
            if (t < lens_s[m]) pool[m][j] = fmaxf(pool[m][j], hn);
        }
        bar_lds();
#pragma unroll
        for (int kt = 0; kt < 5; ++kt) af[kt] = *(const half8*)&hbuf[lr][kt * 32 + lq * 8];
    }
    for (int idx = tid; idx < 2400; idx += 512) {
        int j = idx >> 4, m = idx & 15;
        sent[(size_t)(sb + m) * 300 + (dir ? 150 : 0) + j] = pool[m][j];
    }
}

// ---------------------------------------------------------------------------
// K4a: per sentence: ex softmax(7), ex_pre argmax, avg_lab, build A2 fp32
// ---------------------------------------------------------------------------
__global__ void k4a(const float* __restrict__ sent, const float* __restrict__ w_ex,
                    const float* __restrict__ b_ex, const float* __restrict__ lab,
                    float* __restrict__ A2, int* __restrict__ expre) {
    int n = blockIdx.x, l = threadIdx.x;
    float s[5];
#pragma unroll
    for (int i = 0; i < 5; ++i) { int d = l + 64 * i; s[i] = (d < 300) ? sent[(size_t)n * 300 + d] : 0.0f; }
    float logit[7];
#pragma unroll
    for (int c = 0; c < 7; ++c) {
        float p = 0.0f;
#pragma unroll
        for (int i = 0; i < 5; ++i) { int d = l + 64 * i; if (d < 300) p += s[i] * w_ex[c * 300 + d]; }
#pragma unroll
        for (int off = 32; off > 0; off >>= 1) p += __shfl_xor(p, off);
        logit[c] = p + b_ex[c];
    }
    float mx = logit[0];
#pragma unroll
    for (int c = 1; c < 7; ++c) mx = fmaxf(mx, logit[c]);
    float e[7], ssum = 0.0f;
#pragma unroll
    for (int c = 0; c < 7; ++c) { e[c] = ex2_(LOG2E * (logit[c] - mx)); ssum += e[c]; }
    int best = 0;
#pragma unroll
    for (int c = 1; c < 7; ++c) if (logit[c] > logit[best]) best = c;
    if (l == 0) expre[n] = best;
    float inv = rcp_(ssum);
#pragma unroll
    for (int i = 0; i < 5; ++i) {
        int d = l + 64 * i;
        if (d < 300) {
            float al = 0.0f;
#pragma unroll
            for (int c = 0; c < 7; ++c) al += e[c] * inv * lab[c * 300 + d];
            A2[(size_t)n * 640 + d] = s[i];
            A2[(size_t)n * 640 + 300 + d] = al;
        }
    }
    if (l < 40) A2[(size_t)n * 640 + 600 + l] = 0.0f;
}

// ---------------------------------------------------------------------------
// K5: score softmax over N, exact top-512, penalty partial, mixed build.
// ---------------------------------------------------------------------------
__global__ __launch_bounds__(1024) void k5(const float* __restrict__ joint,
                                           const float* __restrict__ sent,
                                           const float* __restrict__ w_sc,
                                           const float* __restrict__ b_sc,
                                           const int* __restrict__ gold,
                                           const int* __restrict__ expre,
                                           float* __restrict__ mixed,
                                           float* __restrict__ pen_out,
                                           float* __restrict__ dout) {
    __shared__ float arr[1024];
    __shared__ float red[1024];
    int n = threadIdx.x;
    const float4* jr = (const float4*)(joint + (size_t)n * 320);
    const float4* wr = (const float4*)w_sc;
    float sc = b_sc[0];
    for (int q = 0; q < 75; ++q) {
        float4 a = jr[q], w = wr[q];
        sc += a.x * w.x + a.y * w.y + a.z * w.z + a.w * w.w;
    }
    float sg = sigm_(sc);
    arr[n] = sg;
    red[n] = sg;
    __syncthreads();
    for (int s = 512; s > 0; s >>= 1) { if (n < s) red[n] = fmaxf(red[n], red[n + s]); __syncthreads(); }
    float mx = red[0];
    __syncthreads();
    float ex = ex2_(LOG2E * (sg - mx));
    red[n] = ex;
    __syncthreads();
    for (int s = 512; s > 0; s >>= 1) { if (n < s) red[n] += red[n + s]; __syncthreads(); }
    float score = ex * rcp_(red[0]);
    __syncthreads();
    int cnt = 0;
    for (int j = 0; j < 1024; ++j) {
        float vj = arr[j];
        cnt += (vj > sg) || (vj == sg && j < n);
    }
    bool top = cnt < 512;
    bool wrong = gold[n] != expre[n];
    float contrib = wrong ? (top ? 1.5f * score : 0.0f) : (top ? 0.0f : -1.5f * score);
    red[n] = contrib;
    __syncthreads();
    for (int s = 512; s > 0; s >>= 1) { if (n < s) red[n] += red[n + s]; __syncthreads(); }
    if (n == 0) { pen_out[0] = red[0]; dout[1024] = 0.0f; }
    const float4* sr = (const float4*)(sent + (size_t)n * 300);
    float4* mr = (float4*)(mixed + (size_t)n * 320);
    for (int q = 0; q < 75; ++q) mr[q] = top ? jr[q] : sr[q];
    float4 one = {1.0f, 0.0f, 0.0f, 0.0f};
    mr[75] = one;
    float4 z = {0, 0, 0, 0};
    for (int q = 76; q < 80; ++q) mr[q] = z;
}

// ---------------------------------------------------------------------------
// K7: LSTM2, batch=1, 1024 steps, 2 WGs. Gate-interleaved weights; in-reg
// elementwise; double-buffered h; ONE LDS-only barrier per step (G2 prefetch
// and out2 stores stay in flight across it).
// ---------------------------------------------------------------------------
__global__ __launch_bounds__(640, 1) void lstm2_k(
    const f16* __restrict__ G2f, const f16* __restrict__ G2b,
    const f16* __restrict__ H2f, const f16* __restrict__ H2b,
    float* __restrict__ out2) {
    const int dir = blockIdx.x;
    const f16* G2 = dir ? G2b : G2f;
    const f16* Whh = dir ? H2b : H2f;
    __shared__ f16 hl[2][160];

    const int tid = threadIdx.x;
    const int wv = tid >> 6, ln = tid & 63;
    const int lq = ln >> 4, lr = ln & 15;
    const int jme = wv * 16 + lr;
    for (int i = tid; i < 320; i += 640) ((f16*)hl)[i] = (f16)0.0f;
    __syncthreads();

    float c = 0.0f;

    half8 bf[4][5];
#pragma unroll
    for (int g = 0; g < 4; ++g)
#pragma unroll
        for (int kt = 0; kt < 5; ++kt)
            bf[g][kt] = *(const half8*)(Whh + (size_t)(wv * 64 + g * 16 + lr) * 160 + kt * 32 + lq * 8);

    f16 gpre[4];
    {
        int r0 = dir ? 1023 : 0;
#pragma unroll
        for (int g = 0; g < 4; ++g) gpre[g] = G2[(size_t)r0 * 640 + wv * 64 + g * 16 + lr];
    }

    for (int step = 0; step < 1024; ++step) {
        const int row = dir ? (1023 - step) : step;
        const int p = step & 1;
        half8 af[5];
#pragma unroll
        for (int kt = 0; kt < 5; ++kt) af[kt] = *(const half8*)&hl[p][kt * 32 + lq * 8];
        float gate[4];
#pragma unroll
        for (int g = 0; g < 4; ++g) {
            float g0 = (float)gpre[g];
            floatx4 a0 = {g0, g0, g0, g0};
            floatx4 a1 = {0, 0, 0, 0};
            a0 = MFMA16(af[0], bf[g][0], a0);
            a1 = MFMA16(af[1], bf[g][1], a1);
            a0 = MFMA16(af[2], bf[g][2], a0);
            a1 = MFMA16(af[3], bf[g][3], a1);
            a0 = MFMA16(af[4], bf[g][4], a0);
            gate[g] = a0[0] + a1[0];
        }
        {
            int nr = dir ? max(1022 - step, 0) : min(step + 1, 1023);
#pragma unroll
            for (int g = 0; g < 4; ++g) gpre[g] = G2[(size_t)nr * 640 + wv * 64 + g * 16 + lr];
        }
        float cn = sigm_(gate[1]) * c + sigm_(gate[0]) * tanh_(gate[2]);
        float hn = sigm_(gate[3]) * tanh_(cn);
        c = cn;
        if (lq == 0 && jme < 150) {
            hl[p ^ 1][jme] = (f16)hn;
            out2[(size_t)row * 300 + dir * 150 + jme] = hn;
        }
        bar_lds();
    }
}

// ---------------------------------------------------------------------------
// K8: tag logits, log_softmax, argmax -> d_out[0..1023]; CE partial + pen
// ---------------------------------------------------------------------------
__global__ __launch_bounds__(256) void k8(const float* __restrict__ out2,
                                          const float* __restrict__ w_tag,
                                          const float* __restrict__ b_tag,
                                          const int* __restrict__ gold,
                                          const float* __restrict__ pen,
                                          float* __restrict__ dout) {
    __shared__ float wt[7][304];
    __shared__ float red[128];
    const int tid = threadIdx.x;
    for (int i = tid; i < 2100; i += 256) wt[i / 300][i % 300] = w_tag[i];
    __syncthreads();
    float ce = 0.0f;
    if (tid < 128) {
        int n = blockIdx.x * 128 + tid;
        float lg[7];
#pragma unroll
        for (int c = 0; c < 7; ++c) lg[c] = b_tag[c];
        const float4* orow = (const float4*)(out2 + (size_t)n * 300);
        for (int q = 0; q < 75; ++q) {
            float4 v = orow[q];
#pragma unroll
            for (int c = 0; c < 7; ++c)
                lg[c] += v.x * wt[c][q * 4] + v.y * wt[c][q * 4 + 1] +
                         v.z * wt[c][q * 4 + 2] + v.w * wt[c][q * 4 + 3];
        }
        float mx = lg[0];
#pragma unroll
        for (int c = 1; c < 7; ++c) mx = fmaxf(mx, lg[c]);
        float se = 0.0f;
#pragma unroll
        for (int c = 0; c < 7; ++c) se += ex2_(LOG2E * (lg[c] - mx));
        float lse = logf(se);
        int best = 0;
#pragma unroll
        for (int c = 1; c < 7; ++c) if (lg[c] > lg[best]) best = c;
        dout[n] = (float)best;
        ce = -(lg[gold[n]] - mx - lse);
    }
    if (tid < 128) red[tid] = ce;
    __syncthreads();
    for (int s = 64; s > 0; s >>= 1) { if (tid < s) red[tid] += red[tid + s]; __syncthreads(); }
    if (tid == 0) atomicAdd(&dout[1024], red[0] + (blockIdx.x == 0 ? pen[0] : 0.0f));
}

// ---------------------------------------------------------------------------
extern "C" void kernel_launch(void* const* d_in, const int* in_sizes, int n_in,
                              void* d_out, int out_size, void* d_ws, size_t ws_size,
                              hipStream_t stream) {
    const float* x       = (const float*)d_in[0];
    const int*   lengths = (const int*)d_in[1];
    const int*   gold    = (const int*)d_in[2];
    const float* w1f_ih  = (const float*)d_in[3];
    const float* w1f_hh  = (const float*)d_in[4];
    const float* b1f     = (const float*)d_in[5];
    const float* w1b_ih  = (const float*)d_in[6];
    const float* w1b_hh  = (const float*)d_in[7];
    const float* b1b     = (const float*)d_in[8];
    const float* lab     = (const float*)d_in[9];
    const float* w_ex    = (const float*)d_in[10];
    const float* b_ex    = (const float*)d_in[11];
    const float* w_mlp   = (const float*)d_in[12];
    const float* b_mlp   = (const float*)d_in[13];
    const float* w_sc    = (const float*)d_in[14];
    const float* b_sc    = (const float*)d_in[15];
    const float* w2f_ih  = (const float*)d_in[16];
    const float* w2f_hh  = (const float*)d_in[17];
    const float* b2f     = (const float*)d_in[18];
    const float* w2b_ih  = (const float*)d_in[19];
    const float* w2b_hh  = (const float*)d_in[20];
    const float* b2b     = (const float*)d_in[21];
    const float* w_tag   = (const float*)d_in[22];
    const float* b_tag   = (const float*)d_in[23];
    float* dout = (float*)d_out;
    char* ws = (char*)d_ws;

    size_t o = 0;
    auto alloc = [&](size_t bytes) { size_t r = o; o += (bytes + 255) & ~(size_t)255; return r; };
    size_t W1F  = alloc(640 * 320 * 2);
    size_t W1B  = alloc(640 * 320 * 2);
    size_t WMLP = alloc(320 * 640 * 2);
    size_t W2F  = alloc(640 * 320 * 2);
    size_t W2B  = alloc(640 * 320 * 2);
    size_t H1F  = alloc(640 * 160 * 2);
    size_t H1B  = alloc(640 * 160 * 2);
    size_t H2F  = alloc(640 * 160 * 2);
    size_t H2B  = alloc(640 * 160 * 2);
    size_t COFF = alloc(1024 * 4);
    size_t SENT = alloc((size_t)1024 * 300 * 4);
    size_t A2   = alloc((size_t)1024 * 640 * 4);
    size_t EXP  = alloc(1024 * 4);
    size_t JNT  = alloc((size_t)1024 * 320 * 4);
    size_t MIX  = alloc((size_t)1024 * 320 * 4);
    size_t G2F  = alloc((size_t)1024 * 640 * 2);
    size_t G2B  = alloc((size_t)1024 * 640 * 2);
    size_t OUT2 = alloc((size_t)1024 * 300 * 4);
    size_t PEN  = alloc(256);
    const size_t XGSZ = (size_t)131072 * 640 * 2;
    size_t XGF = alloc(XGSZ);
    bool bigws = (o + XGSZ) <= ws_size;
    size_t XGB = bigws ? alloc(XGSZ) : XGF;
    (void)in_sizes; (void)n_in; (void)out_size;

    PackA pa;
    pa.s[0] = w1f_ih; pa.d[0] = (f16*)(ws + W1F);
    pa.s[1] = w1b_ih; pa.d[1] = (f16*)(ws + W1B);
    pa.s[2] = w_mlp;  pa.d[2] = (f16*)(ws + WMLP);
    pa.s[3] = w2f_ih; pa.d[3] = (f16*)(ws + W2F);
    pa.s[4] = w2b_ih; pa.d[4] = (f16*)(ws + W2B);
    pa.s[5] = w1f_hh; pa.d[5] = (f16*)(ws + H1F);
    pa.s[6] = w1b_hh; pa.d[6] = (f16*)(ws + H1B);
    pa.s[7] = w2f_hh; pa.d[7] = (f16*)(ws + H2F);
    pa.s[8] = w2b_hh; pa.d[8] = (f16*)(ws + H2B);
    pa.bb[0] = b2f;   pa.bb[1] = b2b;
    pack_k<<<dim3(800, 9), 256, 0, stream>>>(pa);
    scan_k<<<1, 1024, 0, stream>>>(lengths, (int*)(ws + COFF));

    const int* coffp = (const int*)(ws + COFF);
    if (bigws) {
        gemm2_nt<true><<<dim3(1024, 4), 256, 0, stream>>>(
            x, 300, 300, 10,
            (const f16*)(ws + W1F), b1f, (f16*)(ws + XGF),
            (const f16*)(ws + W1B), b1b, (f16*)(ws + XGB),
            640, lengths, coffp);
        lstm1_k<<<dim3(64, 2), 512, 0, stream>>>(
            (const f16*)(ws + XGF), (const f16*)(ws + XGB),
            (const f16*)(ws + H1F), (const f16*)(ws + H1B),
            (float*)(ws + SENT), lengths, coffp, 0);
    } else {
        gemm2_nt<true><<<dim3(1024, 2), 256, 0, stream>>>(
            x, 300, 300, 10,
            (const f16*)(ws + W1F), b1f, (f16*)(ws + XGF),
            (const f16*)(ws + W1F), b1f, (f16*)(ws + XGF),
            640, lengths, coffp);
        lstm1_k<<<dim3(64, 1), 512, 0, stream>>>(
            (const f16*)(ws + XGF), (const f16*)(ws + XGF),
            (const f16*)(ws + H1F), (const f16*)(ws + H1F),
            (float*)(ws + SENT), lengths, coffp, 0);
        gemm2_nt<true><<<dim3(1024, 2), 256, 0, stream>>>(
            x, 300, 300, 10,
            (const f16*)(ws + W1B), b1b, (f16*)(ws + XGF),
            (const f16*)(ws + W1B), b1b, (f16*)(ws + XGF),
            640, lengths, coffp);
        lstm1_k<<<dim3(64, 1), 512, 0, stream>>>(
            (const f16*)(ws + XGF), (const f16*)(ws + XGF),
            (const f16*)(ws + H1B), (const f16*)(ws + H1B),
            (float*)(ws + SENT), lengths, coffp, 1);
    }

    k4a<<<1024, 64, 0, stream>>>((const float*)(ws + SENT), w_ex, b_ex, lab,
                                 (float*)(ws + A2), (int*)(ws + EXP));
    gemm_mlp<<<8, 256, 0, stream>>>((const float*)(ws + A2), 640, 20,
                                    (const f16*)(ws + WMLP), b_mlp,
                                    (float*)(ws + JNT), 320);
    k5<<<1, 1024, 0, stream>>>((const float*)(ws + JNT), (const float*)(ws + SENT),
                               w_sc, b_sc, gold, (const int*)(ws + EXP),
                               (float*)(ws + MIX), (float*)(ws + PEN), dout);

    gemm2_nt<false><<<dim3(8, 4), 256, 0, stream>>>(
        (const float*)(ws + MIX), 320, 320, 10,
        (const f16*)(ws + W2F), nullptr, (f16*)(ws + G2F),
        (const f16*)(ws + W2B), nullptr, (f16*)(ws + G2B),
        640, nullptr, nullptr);
    lstm2_k<<<2, 640, 0, stream>>>((const f16*)(ws + G2F), (const f16*)(ws + G2B),
                                   (const f16*)(ws + H2F), (const f16*)(ws + H2B),
                                   (float*)(ws + OUT2));

    k8<<<8, 256, 0, stream>>>((const float*)(ws + OUT2), w_tag, b_tag, gold,
                              (const float*)(ws + PEN), dout);
}